// Round 10
// baseline (1269.786 us; speedup 1.0000x reference)
//
#include <hip/hip_runtime.h>
#include <math.h>

#define Bv 256
#define Sv 128
#define Cv 256
#define Tv 64
#define Dv 300
#define Hv 150
#define G4v 600   // 4*H

typedef _Float16 h8v __attribute__((ext_vector_type(8)));
typedef _Float16 h4v __attribute__((ext_vector_type(4)));
typedef float    f4v __attribute__((ext_vector_type(4)));
typedef float    f2v __attribute__((ext_vector_type(2)));

// ------------------------------------------------------------------
// FUSED: fp32 [rows][300] -> fp16 [rows][320] (pad zero) + row L2 norm.
// One wave per row; single read of the embedding (replaces conv+norm).
// ------------------------------------------------------------------
__global__ __launch_bounds__(256)
void fused_cn_k(const float* __restrict__ A, int rows,
                _Float16* __restrict__ A16, float* __restrict__ nrm)
{
    int gtid = blockIdx.x * 256 + threadIdx.x;
    int row  = gtid >> 6;
    int lane = threadIdx.x & 63;
    if (row >= rows) return;
    const float* rp = A   + (size_t)row * Dv;
    _Float16*    op = A16 + (size_t)row * 320;
    float s = 0.f;
    #pragma unroll
    for (int i4 = lane; i4 < 80; i4 += 64) {       // 75 real float4 + 5 pad
        int k = i4 * 4;
        float4 v = {0.f, 0.f, 0.f, 0.f};
        if (k < Dv) v = *(const float4*)&rp[k];    // 300 = 75*4 exactly
        h4v o;
        o[0] = (_Float16)v.x; o[1] = (_Float16)v.y;
        o[2] = (_Float16)v.z; o[3] = (_Float16)v.w;
        *(h4v*)&op[k] = o;
        s += v.x*v.x + v.y*v.y + v.z*v.z + v.w*v.w;
    }
    #pragma unroll
    for (int off = 32; off > 0; off >>= 1) s += __shfl_down(s, off, 64);
    if (lane == 0) nrm[row] = fmaxf(sqrtf(s), 1e-8f);
}

// ------------------------------------------------------------------
// Wx fp32 [300][600] -> W16T fp16 [dir][640][320] transposed, zero-padded
// ------------------------------------------------------------------
__global__ __launch_bounds__(320)
void conv_w16_k(const float* __restrict__ Wf, const float* __restrict__ Wb,
                _Float16* __restrict__ W16T)
{
    const int n   = blockIdx.x;      // 0..639
    const int dir = blockIdx.y;      // 0..1
    const int k   = threadIdx.x;     // 0..319
    const float* W = dir ? Wb : Wf;
    float v = (k < Dv && n < G4v) ? W[(size_t)k * G4v + n] : 0.f;
    W16T[((size_t)dir * 640 + n) * 320 + k] = (_Float16)v;
}

// ------------------------------------------------------------------
// MFMA input projection: G16[dir][s][b][0:600] (fp16) = src @ Wx_dir + b_dir
// ------------------------------------------------------------------
__global__ __launch_bounds__(256)
void gemm_xw_mfma_k(const _Float16* __restrict__ A16,
                    const _Float16* __restrict__ W16T,
                    const float* __restrict__ bf, const float* __restrict__ bb,
                    _Float16* __restrict__ Gout)
{
    const int m0  = blockIdx.x * 128;
    const int n0  = blockIdx.y * 128;
    const int dir = blockIdx.z;
    const float* bias = dir ? bb : bf;
    const _Float16* Wd = W16T + (size_t)dir * 640 * 320;

    __shared__ _Float16 As[128][40];
    __shared__ _Float16 Bs[128][40];

    const int tid  = threadIdx.x;
    const int lane = tid & 63;
    const int w    = tid >> 6;
    const int wm   = w >> 1, wn = w & 1;
    const int r16  = lane & 15, q = lane >> 4;

    const int srow  = tid >> 1;
    const int sslot = (tid & 1) * 16;

    f4v acc[4][4];
    #pragma unroll
    for (int i = 0; i < 4; ++i)
        #pragma unroll
        for (int j = 0; j < 4; ++j) acc[i][j] = (f4v){0.f,0.f,0.f,0.f};

    for (int k0 = 0; k0 < 320; k0 += 32) {
        h8v av0 = *(const h8v*)&A16[(size_t)(m0 + srow) * 320 + k0 + sslot];
        h8v av1 = *(const h8v*)&A16[(size_t)(m0 + srow) * 320 + k0 + sslot + 8];
        h8v bv0 = *(const h8v*)&Wd [(size_t)(n0 + srow) * 320 + k0 + sslot];
        h8v bv1 = *(const h8v*)&Wd [(size_t)(n0 + srow) * 320 + k0 + sslot + 8];
        __syncthreads();
        *(h8v*)&As[srow][sslot]     = av0;
        *(h8v*)&As[srow][sslot + 8] = av1;
        *(h8v*)&Bs[srow][sslot]     = bv0;
        *(h8v*)&Bs[srow][sslot + 8] = bv1;
        __syncthreads();

        h8v af[4], bfr[4];
        #pragma unroll
        for (int mi = 0; mi < 4; ++mi)
            af[mi] = *(const h8v*)&As[wm*64 + mi*16 + r16][q*8];
        #pragma unroll
        for (int ni = 0; ni < 4; ++ni)
            bfr[ni] = *(const h8v*)&Bs[wn*64 + ni*16 + r16][q*8];
        #pragma unroll
        for (int mi = 0; mi < 4; ++mi)
            #pragma unroll
            for (int ni = 0; ni < 4; ++ni)
                acc[mi][ni] = __builtin_amdgcn_mfma_f32_16x16x32_f16(
                                  af[mi], bfr[ni], acc[mi][ni], 0, 0, 0);
    }

    #pragma unroll
    for (int ni = 0; ni < 4; ++ni) {
        int n = n0 + wn*64 + ni*16 + r16;
        if (n >= G4v) continue;
        float bn = bias[n];
        #pragma unroll
        for (int mi = 0; mi < 4; ++mi) {
            #pragma unroll
            for (int r = 0; r < 4; ++r) {
                int row = m0 + wm*64 + mi*16 + q*4 + r;
                int b   = row >> 7;
                int s   = row & 127;
                Gout[(((size_t)dir * Sv + s) * Bv + b) * G4v + n] =
                    (_Float16)(acc[mi][ni][r] + bn);
            }
        }
    }
}

// ------------------------------------------------------------------
// fast transcendentals (validated r8/r9: absmax unchanged at 0.03125)
// ------------------------------------------------------------------
__device__ __forceinline__ float sigm_f(float x)
{
    return __builtin_amdgcn_rcpf(1.f + __expf(-x));
}
__device__ __forceinline__ float tanh_f(float x)
{
    float e = __expf(-2.f * __builtin_fabsf(x));
    float r = (1.f - e) * __builtin_amdgcn_rcpf(1.f + e);
    return __builtin_copysignf(r, x);
}

// ------------------------------------------------------------------
// MFMA LSTM recurrence v5: v4 structure but 512 blocks x 1 batch.
// 2 blocks/CU -> two INDEPENDENT recurrence streams interleave on each
// SIMD (uncorrelated phases hide each other's chain stalls; v4's single
// block/CU had all waves phase-locked). Only rp==0 lanes own the batch;
// h_sh rows 1..15 provably stay zero (c=0 fixed point of the gate math).
// ------------------------------------------------------------------
__global__ __launch_bounds__(640, 5)
void lstm_mfma_k(const _Float16* __restrict__ G16,  // [2][S][B][600] fp16
                 const float* __restrict__ Wh_f, const float* __restrict__ Wh_b,
                 float* __restrict__ out_src,       // [B][S][300]
                 float* __restrict__ out_cell)      // [B][300]
{
    const int blk = blockIdx.x;          // 0..511
    const int dir = blk & 1;
    const int b   = blk >> 1;            // 0..255
    const float* Wh = dir ? Wh_b : Wh_f;
    const _Float16* Gd = G16 + (size_t)dir * Sv * Bv * G4v;

    const int tid  = threadIdx.x;
    const int w    = tid >> 6;           // wave 0..9
    const int lane = tid & 63;
    const int q    = lane >> 4;          // 0..3
    const int cp   = lane & 15;          // 0..15
    const int hcol = w * 16 + cp;        // 0..159
    const bool colok = (hcol < Hv);
    const int hc   = colok ? hcol : 0;   // clamped (dead lanes read real data)
    const int rp   = q;                  // batch row: only rp==0 valid
    const bool bok = (rp == 0);

    __shared__ _Float16 h_sh[2][16][168];
    __shared__ float    g_sh[10][4][16][4];   // [wave][gate][col][row]

    // ---- one-time: Wh B-fragments in registers ----
    h8v Bf[4][5];
    #pragma unroll
    for (int g = 0; g < 4; ++g) {
        #pragma unroll
        for (int ks = 0; ks < 5; ++ks) {
            h8v v;
            #pragma unroll
            for (int j = 0; j < 8; ++j) {
                int k = 32*ks + 8*q + j;
                float x = (k < Hv && colok) ? Wh[(size_t)k * G4v + g*Hv + hcol] : 0.f;
                v[j] = (_Float16)x;
            }
            Bf[g][ks] = v;
        }
    }

    for (int i = tid; i < 2*16*168; i += 640)
        ((_Float16*)h_sh)[i] = (_Float16)0.f;

    float c = 0.f;

    // ---- prologue: prefetch G for steps 0 and 1 (depth 2) ----
    _Float16 gA[4], gB[4];
    #pragma unroll
    for (int g = 0; g < 4; ++g) { gA[g] = (_Float16)0.f; gB[g] = (_Float16)0.f; }
    if (bok) {
        int ss0 = dir ? (Sv - 1) : 0;
        int ss1 = dir ? (Sv - 2) : 1;
        const _Float16* p0 = Gd + ((size_t)ss0 * Bv + b) * G4v;
        const _Float16* p1 = Gd + ((size_t)ss1 * Bv + b) * G4v;
        #pragma unroll
        for (int g = 0; g < 4; ++g) {
            gA[g] = p0[g*Hv + hc];
            gB[g] = p1[g*Hv + hc];
        }
    }
    __syncthreads();

    int cur = 0;
    for (int s = 0; s < Sv; ++s) {
        const int ss = dir ? (Sv - 1 - s) : s;

        // ---- prefetch G for step s+2 ----
        _Float16 gC[4];
        #pragma unroll
        for (int g = 0; g < 4; ++g) gC[g] = (_Float16)0.f;
        if (bok && s + 2 < Sv) {
            int ss2 = dir ? (ss - 2) : (ss + 2);
            const _Float16* p = Gd + ((size_t)ss2 * Bv + b) * G4v;
            #pragma unroll
            for (int g = 0; g < 4; ++g) gC[g] = p[g*Hv + hc];
        }

        // ---- MFMA: h @ Wh (A = h from LDS, B = Wh registers) ----
        f4v a0 = {0.f,0.f,0.f,0.f}, a1 = a0, a2 = a0, a3 = a0;
        #pragma unroll
        for (int ks = 0; ks < 5; ++ks) {
            h8v af = *(const h8v*)&h_sh[cur][cp][32*ks + 8*q];
            a0 = __builtin_amdgcn_mfma_f32_16x16x32_f16(af, Bf[0][ks], a0, 0, 0, 0);
            a1 = __builtin_amdgcn_mfma_f32_16x16x32_f16(af, Bf[1][ks], a1, 0, 0, 0);
            a2 = __builtin_amdgcn_mfma_f32_16x16x32_f16(af, Bf[2][ks], a2, 0, 0, 0);
            a3 = __builtin_amdgcn_mfma_f32_16x16x32_f16(af, Bf[3][ks], a3, 0, 0, 0);
        }

        // ---- wave-private transpose (q==0 lanes hold rows 0..3) ----
        if (q == 0) {
            *(f4v*)&g_sh[w][0][cp][0] = a0;
            *(f4v*)&g_sh[w][1][cp][0] = a1;
            *(f4v*)&g_sh[w][2][cp][0] = a2;
            *(f4v*)&g_sh[w][3][cp][0] = a3;
        }
        float gi = g_sh[w][0][cp][rp] + (float)gA[0];
        float gf = g_sh[w][1][cp][rp] + (float)gA[1];
        float gg = g_sh[w][2][cp][rp] + (float)gA[2];
        float go = g_sh[w][3][cp][rp] + (float)gA[3];

        float I  = sigm_f(gi);
        float F  = sigm_f(gf);
        float Gt = tanh_f(gg);
        float O  = sigm_f(go);
        c = F * c + I * Gt;
        float h = O * tanh_f(c);

        h_sh[cur ^ 1][rp][hcol] = (_Float16)h;   // rp>0 lanes write zeros
        if (bok && colok)
            out_src[((size_t)b * Sv + ss) * (2*Hv) + dir*Hv + hcol] = h;

        #pragma unroll
        for (int g = 0; g < 4; ++g) { gA[g] = gB[g]; gB[g] = gC[g]; }
        cur ^= 1;

        // lgkmcnt-only barrier (LDS visibility; VMEM prefetch stays in flight)
        asm volatile("s_waitcnt lgkmcnt(0)" ::: "memory");
        __builtin_amdgcn_s_barrier();
        __builtin_amdgcn_sched_barrier(0);
    }

    if (bok && colok)
        out_cell[(size_t)b * (2*Hv) + dir*Hv + hcol] = c;
}

// ------------------------------------------------------------------
// transpose src_encoding: out_src fp32 [B][S][300] -> hi/lo fp16 [B][320][128]
// ------------------------------------------------------------------
__global__ __launch_bounds__(256)
void trans_enc_k(const float* __restrict__ enc,
                 _Float16* __restrict__ hi, _Float16* __restrict__ lo)
{
    const int b  = blockIdx.z;
    const int s0 = blockIdx.x * 64;
    const int n0 = blockIdx.y * 64;
    __shared__ float t[64][65];
    const int tid = threadIdx.x;
    const int j  = tid & 63;
    const int i0 = (tid >> 6) * 16;
    #pragma unroll
    for (int ii = 0; ii < 16; ++ii) {
        int i = i0 + ii;
        int n = n0 + j;
        t[i][j] = (n < Dv) ? enc[((size_t)b*Sv + s0 + i)*Dv + n] : 0.f;
    }
    __syncthreads();
    #pragma unroll
    for (int ii = 0; ii < 16; ++ii) {
        int nr = i0 + ii;
        float v = t[j][nr];
        _Float16 hh = (_Float16)v;
        float l = v - (float)hh;
        size_t o = ((size_t)b*320 + n0 + nr)*128 + s0 + j;
        hi[o] = hh;
        lo[o] = (_Float16)l;
    }
}

// ------------------------------------------------------------------
// MFMA cosine-sim: sim16[b][m][s] = (cmp16[b,m,:].src16[b,s,:])/(cn*sn)
// ------------------------------------------------------------------
__global__ __launch_bounds__(256)
void gemm_sim_mfma_k(const _Float16* __restrict__ cmp16,  // [Bz][M][320]
                     const _Float16* __restrict__ src16,  // [B*128][320]
                     const float* __restrict__ cn, const float* __restrict__ sn,
                     int M, _Float16* __restrict__ sim16) // [Bz][M][128]
{
    const int m0 = blockIdx.x * 128;
    const int b  = blockIdx.z;
    const _Float16* A  = cmp16 + (size_t)b * M * 320;
    const _Float16* Bm = src16 + (size_t)b * 128 * 320;

    __shared__ _Float16 As[128][40];
    __shared__ _Float16 Bs[128][40];

    const int tid  = threadIdx.x;
    const int lane = tid & 63;
    const int w    = tid >> 6;
    const int wm   = w >> 1, wn = w & 1;
    const int r16  = lane & 15, q = lane >> 4;

    const int srow  = tid >> 1;
    const int sslot = (tid & 1) * 16;
    const int arow  = (m0 + srow < M) ? (m0 + srow) : 0;

    f4v acc[4][4];
    #pragma unroll
    for (int i = 0; i < 4; ++i)
        #pragma unroll
        for (int j = 0; j < 4; ++j) acc[i][j] = (f4v){0.f,0.f,0.f,0.f};

    for (int k0 = 0; k0 < 320; k0 += 32) {
        h8v av0 = *(const h8v*)&A [(size_t)arow * 320 + k0 + sslot];
        h8v av1 = *(const h8v*)&A [(size_t)arow * 320 + k0 + sslot + 8];
        h8v bv0 = *(const h8v*)&Bm[(size_t)srow * 320 + k0 + sslot];
        h8v bv1 = *(const h8v*)&Bm[(size_t)srow * 320 + k0 + sslot + 8];
        __syncthreads();
        *(h8v*)&As[srow][sslot]     = av0;
        *(h8v*)&As[srow][sslot + 8] = av1;
        *(h8v*)&Bs[srow][sslot]     = bv0;
        *(h8v*)&Bs[srow][sslot + 8] = bv1;
        __syncthreads();

        h8v af[4], bfr[4];
        #pragma unroll
        for (int mi = 0; mi < 4; ++mi)
            af[mi] = *(const h8v*)&As[wm*64 + mi*16 + r16][q*8];
        #pragma unroll
        for (int ni = 0; ni < 4; ++ni)
            bfr[ni] = *(const h8v*)&Bs[wn*64 + ni*16 + r16][q*8];
        #pragma unroll
        for (int mi = 0; mi < 4; ++mi)
            #pragma unroll
            for (int ni = 0; ni < 4; ++ni)
                acc[mi][ni] = __builtin_amdgcn_mfma_f32_16x16x32_f16(
                                  af[mi], bfr[ni], acc[mi][ni], 0, 0, 0);
    }

    #pragma unroll
    for (int ni = 0; ni < 4; ++ni) {
        int s = wn*64 + ni*16 + r16;
        float snv = sn[(size_t)b * 128 + s];
        #pragma unroll
        for (int mi = 0; mi < 4; ++mi) {
            #pragma unroll
            for (int r = 0; r < 4; ++r) {
                int m = m0 + wm*64 + mi*16 + q*4 + r;
                if (m < M) {
                    float v = acc[mi][ni][r] / (cn[(size_t)b * M + m] * snv);
                    sim16[((size_t)b * M + m) * 128 + s] = (_Float16)v;
                }
            }
        }
    }
}

// ------------------------------------------------------------------
// Fused context + type-encoder epilogue
// ------------------------------------------------------------------
__global__ __launch_bounds__(256, 2)
void gemm_ctx_fused_k(const _Float16* __restrict__ sim16,  // [Bz][M][128]
                      const _Float16* __restrict__ encHi,
                      const _Float16* __restrict__ encLo,  // [B][320][128]
                      const float* __restrict__ emb,       // [Bz][M][300]
                      const float* __restrict__ hot,       // [Bz][M][hd]
                      const float* __restrict__ W,         // [hd][300]
                      const float* __restrict__ bias,      // [300]
                      int M, int hd, float* __restrict__ outp)
{
    const int b  = blockIdx.z;
    const int m0 = blockIdx.x * 64;
    const int tid = threadIdx.x;
    const int lane = tid & 63;
    const int w = tid >> 6;
    const int q = lane >> 4, cp = lane & 15;

    __shared__ _Float16 As[64][136];
    __shared__ float Wsh[9*304];
    __shared__ float bsh[304];
    __shared__ float hotsh[64*9];

    {
        const int srow = tid >> 2;
        const int scol = (tid & 3) * 32;
        const _Float16* src = sim16 + ((size_t)b * M + m0 + srow) * 128 + scol;
        *(h8v*)&As[srow][scol]      = *(const h8v*)&src[0];
        *(h8v*)&As[srow][scol + 8]  = *(const h8v*)&src[8];
        *(h8v*)&As[srow][scol + 16] = *(const h8v*)&src[16];
        *(h8v*)&As[srow][scol + 24] = *(const h8v*)&src[24];
    }
    for (int i = tid; i < hd*304; i += 256) {
        int jj = i / 304, nn = i - jj*304;
        Wsh[i] = (nn < Dv) ? W[(size_t)jj * Dv + nn] : 0.f;
    }
    for (int i = tid; i < 304; i += 256) bsh[i] = (i < Dv) ? bias[i] : 0.f;
    for (int i = tid; i < 64*hd; i += 256) hotsh[i] = hot[((size_t)b * M + m0) * hd + i];
    __syncthreads();

    h8v af[4][4];
    #pragma unroll
    for (int mi = 0; mi < 4; ++mi)
        #pragma unroll
        for (int ks = 0; ks < 4; ++ks)
            af[mi][ks] = *(const h8v*)&As[mi*16 + cp][32*ks + 8*q];

    f4v acc[4][5];
    #pragma unroll
    for (int mi = 0; mi < 4; ++mi)
        #pragma unroll
        for (int nt = 0; nt < 5; ++nt) acc[mi][nt] = (f4v){0.f,0.f,0.f,0.f};

    const int nbase = w * 80;
    #pragma unroll
    for (int pass = 0; pass < 2; ++pass) {
        const _Float16* encp = pass ? encLo : encHi;
        #pragma unroll
        for (int nt = 0; nt < 5; ++nt) {
            int n = nbase + nt*16 + cp;
            const _Float16* bp = encp + ((size_t)b * 320 + n) * 128 + 8*q;
            h8v b0 = *(const h8v*)&bp[0];
            h8v b1 = *(const h8v*)&bp[32];
            h8v b2 = *(const h8v*)&bp[64];
            h8v b3 = *(const h8v*)&bp[96];
            #pragma unroll
            for (int mi = 0; mi < 4; ++mi) {
                acc[mi][nt] = __builtin_amdgcn_mfma_f32_16x16x32_f16(af[mi][0], b0, acc[mi][nt], 0, 0, 0);
                acc[mi][nt] = __builtin_amdgcn_mfma_f32_16x16x32_f16(af[mi][1], b1, acc[mi][nt], 0, 0, 0);
                acc[mi][nt] = __builtin_amdgcn_mfma_f32_16x16x32_f16(af[mi][2], b2, acc[mi][nt], 0, 0, 0);
                acc[mi][nt] = __builtin_amdgcn_mfma_f32_16x16x32_f16(af[mi][3], b3, acc[mi][nt], 0, 0, 0);
            }
        }
    }

    #pragma unroll
    for (int nt = 0; nt < 5; ++nt) {
        int n = nbase + nt*16 + cp;
        if (n >= Dv) continue;
        float bn = bsh[n];
        #pragma unroll
        for (int mi = 0; mi < 4; ++mi) {
            #pragma unroll
            for (int r = 0; r < 4; ++r) {
                int ml = mi*16 + 4*q + r;
                int m  = m0 + ml;
                float v = acc[mi][nt][r] + bn + emb[((size_t)b * M + m) * Dv + n];
                for (int jj = 0; jj < hd; ++jj)
                    v = fmaf(hotsh[ml*hd + jj], Wsh[jj*304 + n], v);
                outp[((size_t)b * M + m) * Dv + n] = v;
            }
        }
    }
}

// ------------------------------------------------------------------
extern "C" void kernel_launch(void* const* d_in, const int* in_sizes, int n_in,
                              void* d_out, int out_size, void* d_ws, size_t ws_size,
                              hipStream_t stream)
{
    (void)in_sizes; (void)n_in; (void)out_size; (void)ws_size;
    const float* src_emb = (const float*)d_in[0];
    const float* col_emb = (const float*)d_in[1];
    const float* tab_emb = (const float*)d_in[2];
    const float* col_hot = (const float*)d_in[3];
    const float* tab_hot = (const float*)d_in[4];
    const float* Wx_f = (const float*)d_in[5];
    const float* Wh_f = (const float*)d_in[6];
    const float* b_f  = (const float*)d_in[7];
    const float* Wx_b = (const float*)d_in[8];
    const float* Wh_b = (const float*)d_in[9];
    const float* b_b  = (const float*)d_in[10];
    const float* W_col = (const float*)d_in[11];
    const float* b_col = (const float*)d_in[12];
    const float* W_tab = (const float*)d_in[13];
    const float* b_tab = (const float*)d_in[14];

    float* out      = (float*)d_out;
    float* out_src  = out;                       // [256][128][300]
    float* out_col  = out + 9830400;             // [256][256][300]
    float* out_tab  = out + 29491200;            // [256][64][300]
    float* out_cell = out + 34406400;            // [256][300]

    float* ws = (float*)d_ws;
    _Float16* Gbuf16 = (_Float16*)ws;            // [2][128][256][600] fp16 = 78.6MB
    _Float16* encHi    = (_Float16*)(ws);             // reused AFTER lstm
    _Float16* encLo    = (_Float16*)(ws + 5242880);
    _Float16* sim16_col= (_Float16*)(ws + 11000000);
    _Float16* sim16_tab= (_Float16*)(ws + 16000000);
    float* sn = ws + 39321600;
    float* cn = sn + 32768;
    float* tn = cn + 65536;

    _Float16* A16   = (_Float16*)(out + 9830400);          // [32768][320]
    _Float16* W16T  = A16 + (size_t)32768 * 320;           // [2][640][320]
    _Float16* col16 = (_Float16*)(out + 15278080);         // [65536][320]
    _Float16* tab16 = (_Float16*)(out + 29491200);         // [16384][320]

    // 0. fused fp16 conversion + norms (one read per embedding)
    fused_cn_k<<<32768/4, 256, 0, stream>>>(src_emb, 32768, A16,   sn);
    fused_cn_k<<<65536/4, 256, 0, stream>>>(col_emb, 65536, col16, cn);
    fused_cn_k<<<16384/4, 256, 0, stream>>>(tab_emb, 16384, tab16, tn);
    conv_w16_k<<<dim3(640, 2), 320, 0, stream>>>(Wx_f, Wx_b, W16T);

    // 2. input projection (MFMA, fp16 G output)
    gemm_xw_mfma_k<<<dim3(256, 5, 2), 256, 0, stream>>>(A16, W16T, b_f, b_b, Gbuf16);

    // 3. recurrence (v5: 512 blocks x 1 batch -> 2 independent streams/CU)
    lstm_mfma_k<<<512, 640, 0, stream>>>(Gbuf16, Wh_f, Wh_b, out_src, out_cell);

    // 4. transpose + split src_encoding (G now dead)
    trans_enc_k<<<dim3(2, 5, 256), 256, 0, stream>>>(out_src, encHi, encLo);

    // 5. cosine similarity (MFMA)
    gemm_sim_mfma_k<<<dim3(2, 1, 256), 256, 0, stream>>>(col16, A16, cn, sn, 256, sim16_col);
    gemm_sim_mfma_k<<<dim3(1, 1, 256), 256, 0, stream>>>(tab16, A16, tn, sn, 64,  sim16_tab);

    // 6. fused context + type encoder
    gemm_ctx_fused_k<<<dim3(4, 1, 256), 256, 0, stream>>>(
        sim16_col, encHi, encLo, col_emb, col_hot, W_col, b_col, 256, 9, out_col);
    gemm_ctx_fused_k<<<dim3(1, 1, 256), 256, 0, stream>>>(
        sim16_tab, encHi, encLo, tab_emb, tab_hot, W_tab, b_tab, 64, 5, out_tab);
}

// Round 11
// 609.196 us; speedup vs baseline: 2.0844x; 2.0844x over previous
//
#include <hip/hip_runtime.h>
#include <math.h>

#define Bv 256
#define Sv 128
#define Cv 256
#define Tv 64
#define Dv 300
#define Hv 150
#define G4v 600   // 4*H

typedef _Float16 h8v __attribute__((ext_vector_type(8)));
typedef _Float16 h4v __attribute__((ext_vector_type(4)));
typedef float    f4v __attribute__((ext_vector_type(4)));
typedef float    f2v __attribute__((ext_vector_type(2)));

// ------------------------------------------------------------------
// FUSED: fp32 [rows][300] -> fp16 [rows][320] (pad zero) + row L2 norm.
// ------------------------------------------------------------------
__global__ __launch_bounds__(256)
void fused_cn_k(const float* __restrict__ A, int rows,
                _Float16* __restrict__ A16, float* __restrict__ nrm)
{
    int gtid = blockIdx.x * 256 + threadIdx.x;
    int row  = gtid >> 6;
    int lane = threadIdx.x & 63;
    if (row >= rows) return;
    const float* rp = A   + (size_t)row * Dv;
    _Float16*    op = A16 + (size_t)row * 320;
    float s = 0.f;
    #pragma unroll
    for (int i4 = lane; i4 < 80; i4 += 64) {
        int k = i4 * 4;
        float4 v = {0.f, 0.f, 0.f, 0.f};
        if (k < Dv) v = *(const float4*)&rp[k];
        h4v o;
        o[0] = (_Float16)v.x; o[1] = (_Float16)v.y;
        o[2] = (_Float16)v.z; o[3] = (_Float16)v.w;
        *(h4v*)&op[k] = o;
        s += v.x*v.x + v.y*v.y + v.z*v.z + v.w*v.w;
    }
    #pragma unroll
    for (int off = 32; off > 0; off >>= 1) s += __shfl_down(s, off, 64);
    if (lane == 0) nrm[row] = fmaxf(sqrtf(s), 1e-8f);
}

// ------------------------------------------------------------------
// Wx fp32 [300][600] -> W16T fp16 [dir][640][320] transposed, zero-padded
// ------------------------------------------------------------------
__global__ __launch_bounds__(320)
void conv_w16_k(const float* __restrict__ Wf, const float* __restrict__ Wb,
                _Float16* __restrict__ W16T)
{
    const int n   = blockIdx.x;      // 0..639
    const int dir = blockIdx.y;      // 0..1
    const int k   = threadIdx.x;     // 0..319
    const float* W = dir ? Wb : Wf;
    float v = (k < Dv && n < G4v) ? W[(size_t)k * G4v + n] : 0.f;
    W16T[((size_t)dir * 640 + n) * 320 + k] = (_Float16)v;
}

// ------------------------------------------------------------------
// MFMA input projection v2: B (Wx^T) register-resident per wave.
// 512 thr / 8 waves (grid 2m x 4n -> 64x32 per wave); Bf[2][10] = 80
// VGPR loaded once; A-only LDS tile, double-buffered, 1 barrier/iter.
// ------------------------------------------------------------------
__global__ __launch_bounds__(512)
void gemm_xw_mfma_k(const _Float16* __restrict__ A16,
                    const _Float16* __restrict__ W16T,
                    const float* __restrict__ bf, const float* __restrict__ bb,
                    _Float16* __restrict__ Gout)
{
    const int m0  = blockIdx.x * 128;
    const int n0  = blockIdx.y * 128;
    const int dir = blockIdx.z;
    const float* bias = dir ? bb : bf;
    const _Float16* Wd = W16T + (size_t)dir * 640 * 320;

    __shared__ _Float16 As[2][128][40];

    const int tid  = threadIdx.x;
    const int lane = tid & 63;
    const int w    = tid >> 6;           // 0..7
    const int wm   = w >> 2, wn = w & 3; // 2 x 4 wave grid
    const int r16  = lane & 15, q = lane >> 4;
    const int srow = tid >> 2;           // 0..127
    const int scol = (tid & 3) * 8;      // 0,8,16,24

    // one-time: B-fragments (Wx^T) into registers
    h8v Bf[2][10];
    #pragma unroll
    for (int ni = 0; ni < 2; ++ni)
        #pragma unroll
        for (int ks = 0; ks < 10; ++ks)
            Bf[ni][ks] = *(const h8v*)&Wd[(size_t)(n0 + wn*32 + ni*16 + r16) * 320
                                          + 32*ks + 8*q];

    f4v acc[4][2];
    #pragma unroll
    for (int i = 0; i < 4; ++i)
        #pragma unroll
        for (int j = 0; j < 2; ++j) acc[i][j] = (f4v){0.f,0.f,0.f,0.f};

    // prologue: stage k-tile 0
    *(h8v*)&As[0][srow][scol] = *(const h8v*)&A16[(size_t)(m0 + srow) * 320 + scol];
    __syncthreads();

    for (int it = 0; it < 10; ++it) {
        const int cur = it & 1;
        h8v av;
        if (it + 1 < 10)
            av = *(const h8v*)&A16[(size_t)(m0 + srow) * 320 + (it+1)*32 + scol];

        h8v af[4];
        #pragma unroll
        for (int mi = 0; mi < 4; ++mi)
            af[mi] = *(const h8v*)&As[cur][wm*64 + mi*16 + r16][q*8];
        #pragma unroll
        for (int mi = 0; mi < 4; ++mi)
            #pragma unroll
            for (int ni = 0; ni < 2; ++ni)
                acc[mi][ni] = __builtin_amdgcn_mfma_f32_16x16x32_f16(
                                  af[mi], Bf[ni][it], acc[mi][ni], 0, 0, 0);

        if (it + 1 < 10)
            *(h8v*)&As[cur ^ 1][srow][scol] = av;   // other buffer: no race
        __syncthreads();
    }

    // epilogue: C/D layout col=lane&15, row=4*(lane>>4)+reg
    #pragma unroll
    for (int ni = 0; ni < 2; ++ni) {
        int n = n0 + wn*32 + ni*16 + r16;
        if (n >= G4v) continue;
        float bn = bias[n];
        #pragma unroll
        for (int mi = 0; mi < 4; ++mi) {
            #pragma unroll
            for (int r = 0; r < 4; ++r) {
                int row = m0 + wm*64 + mi*16 + q*4 + r;
                int b   = row >> 7;
                int s   = row & 127;
                Gout[(((size_t)dir * Sv + s) * Bv + b) * G4v + n] =
                    (_Float16)(acc[mi][ni][r] + bn);
            }
        }
    }
}

// ------------------------------------------------------------------
// fast transcendentals (validated r8/r9: absmax unchanged at 0.03125)
// ------------------------------------------------------------------
__device__ __forceinline__ float sigm_f(float x)
{
    return __builtin_amdgcn_rcpf(1.f + __expf(-x));
}
__device__ __forceinline__ float tanh_f(float x)
{
    float e = __expf(-2.f * __builtin_fabsf(x));
    float r = (1.f - e) * __builtin_amdgcn_rcpf(1.f + e);
    return __builtin_copysignf(r, x);
}

// ------------------------------------------------------------------
// MFMA LSTM recurrence — EXACT round-9 version (measured 196 us):
// 128 blocks x 4 batches, launch_bounds(640,1) [84 VGPR, no spill;
// HW can still co-schedule 2 blocks/CU], fp16 G, depth-2 prefetch,
// lgkmcnt-only barrier. Do NOT raise the launch_bounds occupancy arg:
// (640,5) forced 48 VGPR and spilled Bf to scratch (r10: 895 us).
// ------------------------------------------------------------------
__global__ __launch_bounds__(640, 1)
void lstm_mfma_k(const _Float16* __restrict__ G16,  // [2][S][B][600] fp16
                 const float* __restrict__ Wh_f, const float* __restrict__ Wh_b,
                 float* __restrict__ out_src,       // [B][S][300]
                 float* __restrict__ out_cell)      // [B][300]
{
    const int blk = blockIdx.x;          // 0..127
    const int dir = blk & 1;
    const int b0  = (blk >> 1) * 4;
    const float* Wh = dir ? Wh_b : Wh_f;
    const _Float16* Gd = G16 + (size_t)dir * Sv * Bv * G4v;

    const int tid  = threadIdx.x;
    const int w    = tid >> 6;           // wave 0..9
    const int lane = tid & 63;
    const int q    = lane >> 4;          // 0..3
    const int cp   = lane & 15;          // 0..15
    const int hcol = w * 16 + cp;        // 0..159
    const bool colok = (hcol < Hv);
    const int hc   = colok ? hcol : 0;   // clamped (dead lanes read real data)
    const int rp   = q;                  // batch row this lane owns

    __shared__ _Float16 h_sh[2][16][168];
    __shared__ float    g_sh[10][4][16][4];   // [wave][gate][col][row]

    // ---- one-time: Wh B-fragments in registers ----
    h8v Bf[4][5];
    #pragma unroll
    for (int g = 0; g < 4; ++g) {
        #pragma unroll
        for (int ks = 0; ks < 5; ++ks) {
            h8v v;
            #pragma unroll
            for (int j = 0; j < 8; ++j) {
                int k = 32*ks + 8*q + j;
                float x = (k < Hv && colok) ? Wh[(size_t)k * G4v + g*Hv + hcol] : 0.f;
                v[j] = (_Float16)x;
            }
            Bf[g][ks] = v;
        }
    }

    for (int i = tid; i < 2*16*168; i += 640)
        ((_Float16*)h_sh)[i] = (_Float16)0.f;

    float c = 0.f;

    // ---- prologue: prefetch G for steps 0 and 1 (depth 2) ----
    _Float16 gA[4], gB[4];
    {
        int ss0 = dir ? (Sv - 1) : 0;
        int ss1 = dir ? (Sv - 2) : 1;
        const _Float16* p0 = Gd + ((size_t)ss0 * Bv + b0 + rp) * G4v;
        const _Float16* p1 = Gd + ((size_t)ss1 * Bv + b0 + rp) * G4v;
        #pragma unroll
        for (int g = 0; g < 4; ++g) {
            gA[g] = p0[g*Hv + hc];
            gB[g] = p1[g*Hv + hc];
        }
    }
    __syncthreads();

    int cur = 0;
    for (int s = 0; s < Sv; ++s) {
        const int ss = dir ? (Sv - 1 - s) : s;

        // ---- prefetch G for step s+2 ----
        _Float16 gC[4];
        #pragma unroll
        for (int g = 0; g < 4; ++g) gC[g] = (_Float16)0.f;
        if (s + 2 < Sv) {
            int ss2 = dir ? (ss - 2) : (ss + 2);
            const _Float16* p = Gd + ((size_t)ss2 * Bv + b0 + rp) * G4v;
            #pragma unroll
            for (int g = 0; g < 4; ++g) gC[g] = p[g*Hv + hc];
        }

        // ---- MFMA: h @ Wh (A = h from LDS, B = Wh registers) ----
        f4v a0 = {0.f,0.f,0.f,0.f}, a1 = a0, a2 = a0, a3 = a0;
        #pragma unroll
        for (int ks = 0; ks < 5; ++ks) {
            h8v af = *(const h8v*)&h_sh[cur][cp][32*ks + 8*q];
            a0 = __builtin_amdgcn_mfma_f32_16x16x32_f16(af, Bf[0][ks], a0, 0, 0, 0);
            a1 = __builtin_amdgcn_mfma_f32_16x16x32_f16(af, Bf[1][ks], a1, 0, 0, 0);
            a2 = __builtin_amdgcn_mfma_f32_16x16x32_f16(af, Bf[2][ks], a2, 0, 0, 0);
            a3 = __builtin_amdgcn_mfma_f32_16x16x32_f16(af, Bf[3][ks], a3, 0, 0, 0);
        }

        // ---- wave-private transpose (q==0 lanes hold rows 0..3) ----
        if (q == 0) {
            *(f4v*)&g_sh[w][0][cp][0] = a0;
            *(f4v*)&g_sh[w][1][cp][0] = a1;
            *(f4v*)&g_sh[w][2][cp][0] = a2;
            *(f4v*)&g_sh[w][3][cp][0] = a3;
        }
        float gi = g_sh[w][0][cp][rp] + (float)gA[0];
        float gf = g_sh[w][1][cp][rp] + (float)gA[1];
        float gg = g_sh[w][2][cp][rp] + (float)gA[2];
        float go = g_sh[w][3][cp][rp] + (float)gA[3];

        float I  = sigm_f(gi);
        float F  = sigm_f(gf);
        float Gt = tanh_f(gg);
        float O  = sigm_f(go);
        c = F * c + I * Gt;
        float h = O * tanh_f(c);

        h_sh[cur ^ 1][rp][hcol] = (_Float16)h;
        if (colok)
            out_src[(((size_t)(b0 + rp)) * Sv + ss) * (2*Hv) + dir*Hv + hcol] = h;

        #pragma unroll
        for (int g = 0; g < 4; ++g) { gA[g] = gB[g]; gB[g] = gC[g]; }
        cur ^= 1;

        // lgkmcnt-only barrier (LDS visibility; VMEM prefetch stays in flight)
        asm volatile("s_waitcnt lgkmcnt(0)" ::: "memory");
        __builtin_amdgcn_s_barrier();
        __builtin_amdgcn_sched_barrier(0);
    }

    if (colok)
        out_cell[(size_t)(b0 + rp) * (2*Hv) + dir*Hv + hcol] = c;
}

// ------------------------------------------------------------------
// transpose src_encoding: out_src fp32 [B][S][300] -> hi/lo fp16 [B][320][128]
// ------------------------------------------------------------------
__global__ __launch_bounds__(256)
void trans_enc_k(const float* __restrict__ enc,
                 _Float16* __restrict__ hi, _Float16* __restrict__ lo)
{
    const int b  = blockIdx.z;
    const int s0 = blockIdx.x * 64;
    const int n0 = blockIdx.y * 64;
    __shared__ float t[64][65];
    const int tid = threadIdx.x;
    const int j  = tid & 63;
    const int i0 = (tid >> 6) * 16;
    #pragma unroll
    for (int ii = 0; ii < 16; ++ii) {
        int i = i0 + ii;
        int n = n0 + j;
        t[i][j] = (n < Dv) ? enc[((size_t)b*Sv + s0 + i)*Dv + n] : 0.f;
    }
    __syncthreads();
    #pragma unroll
    for (int ii = 0; ii < 16; ++ii) {
        int nr = i0 + ii;
        float v = t[j][nr];
        _Float16 hh = (_Float16)v;
        float l = v - (float)hh;
        size_t o = ((size_t)b*320 + n0 + nr)*128 + s0 + j;
        hi[o] = hh;
        lo[o] = (_Float16)l;
    }
}

// ------------------------------------------------------------------
// MFMA cosine-sim: sim16[b][m][s] = (cmp16[b,m,:].src16[b,s,:])/(cn*sn)
// ------------------------------------------------------------------
__global__ __launch_bounds__(256)
void gemm_sim_mfma_k(const _Float16* __restrict__ cmp16,  // [Bz][M][320]
                     const _Float16* __restrict__ src16,  // [B*128][320]
                     const float* __restrict__ cn, const float* __restrict__ sn,
                     int M, _Float16* __restrict__ sim16) // [Bz][M][128]
{
    const int m0 = blockIdx.x * 128;
    const int b  = blockIdx.z;
    const _Float16* A  = cmp16 + (size_t)b * M * 320;
    const _Float16* Bm = src16 + (size_t)b * 128 * 320;

    __shared__ _Float16 As[128][40];
    __shared__ _Float16 Bs[128][40];

    const int tid  = threadIdx.x;
    const int lane = tid & 63;
    const int w    = tid >> 6;
    const int wm   = w >> 1, wn = w & 1;
    const int r16  = lane & 15, q = lane >> 4;

    const int srow  = tid >> 1;
    const int sslot = (tid & 1) * 16;
    const int arow  = (m0 + srow < M) ? (m0 + srow) : 0;

    f4v acc[4][4];
    #pragma unroll
    for (int i = 0; i < 4; ++i)
        #pragma unroll
        for (int j = 0; j < 4; ++j) acc[i][j] = (f4v){0.f,0.f,0.f,0.f};

    for (int k0 = 0; k0 < 320; k0 += 32) {
        h8v av0 = *(const h8v*)&A [(size_t)arow * 320 + k0 + sslot];
        h8v av1 = *(const h8v*)&A [(size_t)arow * 320 + k0 + sslot + 8];
        h8v bv0 = *(const h8v*)&Bm[(size_t)srow * 320 + k0 + sslot];
        h8v bv1 = *(const h8v*)&Bm[(size_t)srow * 320 + k0 + sslot + 8];
        __syncthreads();
        *(h8v*)&As[srow][sslot]     = av0;
        *(h8v*)&As[srow][sslot + 8] = av1;
        *(h8v*)&Bs[srow][sslot]     = bv0;
        *(h8v*)&Bs[srow][sslot + 8] = bv1;
        __syncthreads();

        h8v af[4], bfr[4];
        #pragma unroll
        for (int mi = 0; mi < 4; ++mi)
            af[mi] = *(const h8v*)&As[wm*64 + mi*16 + r16][q*8];
        #pragma unroll
        for (int ni = 0; ni < 4; ++ni)
            bfr[ni] = *(const h8v*)&Bs[wn*64 + ni*16 + r16][q*8];
        #pragma unroll
        for (int mi = 0; mi < 4; ++mi)
            #pragma unroll
            for (int ni = 0; ni < 4; ++ni)
                acc[mi][ni] = __builtin_amdgcn_mfma_f32_16x16x32_f16(
                                  af[mi], bfr[ni], acc[mi][ni], 0, 0, 0);
    }

    #pragma unroll
    for (int ni = 0; ni < 4; ++ni) {
        int s = wn*64 + ni*16 + r16;
        float snv = sn[(size_t)b * 128 + s];
        #pragma unroll
        for (int mi = 0; mi < 4; ++mi) {
            #pragma unroll
            for (int r = 0; r < 4; ++r) {
                int m = m0 + wm*64 + mi*16 + q*4 + r;
                if (m < M) {
                    float v = acc[mi][ni][r] / (cn[(size_t)b * M + m] * snv);
                    sim16[((size_t)b * M + m) * 128 + s] = (_Float16)v;
                }
            }
        }
    }
}

// ------------------------------------------------------------------
// Fused context + type-encoder epilogue
// ------------------------------------------------------------------
__global__ __launch_bounds__(256, 2)
void gemm_ctx_fused_k(const _Float16* __restrict__ sim16,  // [Bz][M][128]
                      const _Float16* __restrict__ encHi,
                      const _Float16* __restrict__ encLo,  // [B][320][128]
                      const float* __restrict__ emb,       // [Bz][M][300]
                      const float* __restrict__ hot,       // [Bz][M][hd]
                      const float* __restrict__ W,         // [hd][300]
                      const float* __restrict__ bias,      // [300]
                      int M, int hd, float* __restrict__ outp)
{
    const int b  = blockIdx.z;
    const int m0 = blockIdx.x * 64;
    const int tid = threadIdx.x;
    const int lane = tid & 63;
    const int w = tid >> 6;
    const int q = lane >> 4, cp = lane & 15;

    __shared__ _Float16 As[64][136];
    __shared__ float Wsh[9*304];
    __shared__ float bsh[304];
    __shared__ float hotsh[64*9];

    {
        const int srow = tid >> 2;
        const int scol = (tid & 3) * 32;
        const _Float16* src = sim16 + ((size_t)b * M + m0 + srow) * 128 + scol;
        *(h8v*)&As[srow][scol]      = *(const h8v*)&src[0];
        *(h8v*)&As[srow][scol + 8]  = *(const h8v*)&src[8];
        *(h8v*)&As[srow][scol + 16] = *(const h8v*)&src[16];
        *(h8v*)&As[srow][scol + 24] = *(const h8v*)&src[24];
    }
    for (int i = tid; i < hd*304; i += 256) {
        int jj = i / 304, nn = i - jj*304;
        Wsh[i] = (nn < Dv) ? W[(size_t)jj * Dv + nn] : 0.f;
    }
    for (int i = tid; i < 304; i += 256) bsh[i] = (i < Dv) ? bias[i] : 0.f;
    for (int i = tid; i < 64*hd; i += 256) hotsh[i] = hot[((size_t)b * M + m0) * hd + i];
    __syncthreads();

    h8v af[4][4];
    #pragma unroll
    for (int mi = 0; mi < 4; ++mi)
        #pragma unroll
        for (int ks = 0; ks < 4; ++ks)
            af[mi][ks] = *(const h8v*)&As[mi*16 + cp][32*ks + 8*q];

    f4v acc[4][5];
    #pragma unroll
    for (int mi = 0; mi < 4; ++mi)
        #pragma unroll
        for (int nt = 0; nt < 5; ++nt) acc[mi][nt] = (f4v){0.f,0.f,0.f,0.f};

    const int nbase = w * 80;
    #pragma unroll
    for (int pass = 0; pass < 2; ++pass) {
        const _Float16* encp = pass ? encLo : encHi;
        #pragma unroll
        for (int nt = 0; nt < 5; ++nt) {
            int n = nbase + nt*16 + cp;
            const _Float16* bp = encp + ((size_t)b * 320 + n) * 128 + 8*q;
            h8v b0 = *(const h8v*)&bp[0];
            h8v b1 = *(const h8v*)&bp[32];
            h8v b2 = *(const h8v*)&bp[64];
            h8v b3 = *(const h8v*)&bp[96];
            #pragma unroll
            for (int mi = 0; mi < 4; ++mi) {
                acc[mi][nt] = __builtin_amdgcn_mfma_f32_16x16x32_f16(af[mi][0], b0, acc[mi][nt], 0, 0, 0);
                acc[mi][nt] = __builtin_amdgcn_mfma_f32_16x16x32_f16(af[mi][1], b1, acc[mi][nt], 0, 0, 0);
                acc[mi][nt] = __builtin_amdgcn_mfma_f32_16x16x32_f16(af[mi][2], b2, acc[mi][nt], 0, 0, 0);
                acc[mi][nt] = __builtin_amdgcn_mfma_f32_16x16x32_f16(af[mi][3], b3, acc[mi][nt], 0, 0, 0);
            }
        }
    }

    #pragma unroll
    for (int nt = 0; nt < 5; ++nt) {
        int n = nbase + nt*16 + cp;
        if (n >= Dv) continue;
        float bn = bsh[n];
        #pragma unroll
        for (int mi = 0; mi < 4; ++mi) {
            #pragma unroll
            for (int r = 0; r < 4; ++r) {
                int ml = mi*16 + 4*q + r;
                int m  = m0 + ml;
                float v = acc[mi][nt][r] + bn + emb[((size_t)b * M + m) * Dv + n];
                for (int jj = 0; jj < hd; ++jj)
                    v = fmaf(hotsh[ml*hd + jj], Wsh[jj*304 + n], v);
                outp[((size_t)b * M + m) * Dv + n] = v;
            }
        }
    }
}

// ------------------------------------------------------------------
extern "C" void kernel_launch(void* const* d_in, const int* in_sizes, int n_in,
                              void* d_out, int out_size, void* d_ws, size_t ws_size,
                              hipStream_t stream)
{
    (void)in_sizes; (void)n_in; (void)out_size; (void)ws_size;
    const float* src_emb = (const float*)d_in[0];
    const float* col_emb = (const float*)d_in[1];
    const float* tab_emb = (const float*)d_in[2];
    const float* col_hot = (const float*)d_in[3];
    const float* tab_hot = (const float*)d_in[4];
    const float* Wx_f = (const float*)d_in[5];
    const float* Wh_f = (const float*)d_in[6];
    const float* b_f  = (const float*)d_in[7];
    const float* Wx_b = (const float*)d_in[8];
    const float* Wh_b = (const float*)d_in[9];
    const float* b_b  = (const float*)d_in[10];
    const float* W_col = (const float*)d_in[11];
    const float* b_col = (const float*)d_in[12];
    const float* W_tab = (const float*)d_in[13];
    const float* b_tab = (const float*)d_in[14];

    float* out      = (float*)d_out;
    float* out_src  = out;                       // [256][128][300]
    float* out_col  = out + 9830400;             // [256][256][300]
    float* out_tab  = out + 29491200;            // [256][64][300]
    float* out_cell = out + 34406400;            // [256][300]

    float* ws = (float*)d_ws;
    _Float16* Gbuf16 = (_Float16*)ws;            // [2][128][256][600] fp16 = 78.6MB
    _Float16* encHi    = (_Float16*)(ws);             // reused AFTER lstm
    _Float16* encLo    = (_Float16*)(ws + 5242880);
    _Float16* sim16_col= (_Float16*)(ws + 11000000);
    _Float16* sim16_tab= (_Float16*)(ws + 16000000);
    float* sn = ws + 39321600;
    float* cn = sn + 32768;
    float* tn = cn + 65536;

    _Float16* A16   = (_Float16*)(out + 9830400);          // [32768][320]
    _Float16* W16T  = A16 + (size_t)32768 * 320;           // [2][640][320]
    _Float16* col16 = (_Float16*)(out + 15278080);         // [65536][320]
    _Float16* tab16 = (_Float16*)(out + 29491200);         // [16384][320]

    // 0. fused fp16 conversion + norms (one read per embedding)
    fused_cn_k<<<32768/4, 256, 0, stream>>>(src_emb, 32768, A16,   sn);
    fused_cn_k<<<65536/4, 256, 0, stream>>>(col_emb, 65536, col16, cn);
    fused_cn_k<<<16384/4, 256, 0, stream>>>(tab_emb, 16384, tab16, tn);
    conv_w16_k<<<dim3(640, 2), 320, 0, stream>>>(Wx_f, Wx_b, W16T);

    // 2. input projection (MFMA v2: B in registers, fp16 G output)
    gemm_xw_mfma_k<<<dim3(256, 5, 2), 512, 0, stream>>>(A16, W16T, b_f, b_b, Gbuf16);

    // 3. recurrence (exact r9 kernel: 128 blocks, (640,1), 196 us)
    lstm_mfma_k<<<128, 640, 0, stream>>>(Gbuf16, Wh_f, Wh_b, out_src, out_cell);

    // 4. transpose + split src_encoding (G now dead)
    trans_enc_k<<<dim3(2, 5, 256), 256, 0, stream>>>(out_src, encHi, encLo);

    // 5. cosine similarity (MFMA)
    gemm_sim_mfma_k<<<dim3(2, 1, 256), 256, 0, stream>>>(col16, A16, cn, sn, 256, sim16_col);
    gemm_sim_mfma_k<<<dim3(1, 1, 256), 256, 0, stream>>>(tab16, A16, tn, sn, 64,  sim16_tab);

    // 6. fused context + type encoder
    gemm_ctx_fused_k<<<dim3(4, 1, 256), 256, 0, stream>>>(
        sim16_col, encHi, encLo, col_emb, col_hot, W_col, b_col, 256, 9, out_col);
    gemm_ctx_fused_k<<<dim3(1, 1, 256), 256, 0, stream>>>(
        sim16_tab, encHi, encLo, tab_emb, tab_hot, W_tab, b_tab, 64, 5, out_tab);
}

// Round 13
// 570.893 us; speedup vs baseline: 2.2242x; 1.0671x over previous
//
#include <hip/hip_runtime.h>
#include <math.h>

#define Bv 256
#define Sv 128
#define Cv 256
#define Tv 64
#define Dv 300
#define Hv 150
#define G4v 600   // 4*H

typedef _Float16 h8v __attribute__((ext_vector_type(8)));
typedef _Float16 h4v __attribute__((ext_vector_type(4)));
typedef float    f4v __attribute__((ext_vector_type(4)));

// ------------------------------------------------------------------
// FUSED: fp32 [rows][300] -> fp16 [rows][320] (pad zero) + row L2 norm.
// ------------------------------------------------------------------
__global__ __launch_bounds__(256)
void fused_cn_k(const float* __restrict__ A, int rows,
                _Float16* __restrict__ A16, float* __restrict__ nrm)
{
    int gtid = blockIdx.x * 256 + threadIdx.x;
    int row  = gtid >> 6;
    int lane = threadIdx.x & 63;
    if (row >= rows) return;
    const float* rp = A   + (size_t)row * Dv;
    _Float16*    op = A16 + (size_t)row * 320;
    float s = 0.f;
    #pragma unroll
    for (int i4 = lane; i4 < 80; i4 += 64) {
        int k = i4 * 4;
        float4 v = {0.f, 0.f, 0.f, 0.f};
        if (k < Dv) v = *(const float4*)&rp[k];
        h4v o;
        o[0] = (_Float16)v.x; o[1] = (_Float16)v.y;
        o[2] = (_Float16)v.z; o[3] = (_Float16)v.w;
        *(h4v*)&op[k] = o;
        s += v.x*v.x + v.y*v.y + v.z*v.z + v.w*v.w;
    }
    #pragma unroll
    for (int off = 32; off > 0; off >>= 1) s += __shfl_down(s, off, 64);
    if (lane == 0) nrm[row] = fmaxf(sqrtf(s), 1e-8f);
}

// ------------------------------------------------------------------
// Wx fp32 [300][600] -> W16T fp16 [dir][640][320] transposed, zero-padded
// ------------------------------------------------------------------
__global__ __launch_bounds__(320)
void conv_w16_k(const float* __restrict__ Wf, const float* __restrict__ Wb,
                _Float16* __restrict__ W16T)
{
    const int n   = blockIdx.x;      // 0..639
    const int dir = blockIdx.y;      // 0..1
    const int k   = threadIdx.x;     // 0..319
    const float* W = dir ? Wb : Wf;
    float v = (k < Dv && n < G4v) ? W[(size_t)k * G4v + n] : 0.f;
    W16T[((size_t)dir * 640 + n) * 320 + k] = (_Float16)v;
}

// ------------------------------------------------------------------
// MFMA input projection v2 (r11, kept): B register-resident per wave.
// ------------------------------------------------------------------
__global__ __launch_bounds__(512)
void gemm_xw_mfma_k(const _Float16* __restrict__ A16,
                    const _Float16* __restrict__ W16T,
                    const float* __restrict__ bf, const float* __restrict__ bb,
                    _Float16* __restrict__ Gout)
{
    const int m0  = blockIdx.x * 128;
    const int n0  = blockIdx.y * 128;
    const int dir = blockIdx.z;
    const float* bias = dir ? bb : bf;
    const _Float16* Wd = W16T + (size_t)dir * 640 * 320;

    __shared__ _Float16 As[2][128][40];

    const int tid  = threadIdx.x;
    const int lane = tid & 63;
    const int w    = tid >> 6;           // 0..7
    const int wm   = w >> 2, wn = w & 3;
    const int r16  = lane & 15, q = lane >> 4;
    const int srow = tid >> 2;
    const int scol = (tid & 3) * 8;

    h8v Bf[2][10];
    #pragma unroll
    for (int ni = 0; ni < 2; ++ni)
        #pragma unroll
        for (int ks = 0; ks < 10; ++ks)
            Bf[ni][ks] = *(const h8v*)&Wd[(size_t)(n0 + wn*32 + ni*16 + r16) * 320
                                          + 32*ks + 8*q];

    f4v acc[4][2];
    #pragma unroll
    for (int i = 0; i < 4; ++i)
        #pragma unroll
        for (int j = 0; j < 2; ++j) acc[i][j] = (f4v){0.f,0.f,0.f,0.f};

    *(h8v*)&As[0][srow][scol] = *(const h8v*)&A16[(size_t)(m0 + srow) * 320 + scol];
    __syncthreads();

    for (int it = 0; it < 10; ++it) {
        const int cur = it & 1;
        h8v av;
        if (it + 1 < 10)
            av = *(const h8v*)&A16[(size_t)(m0 + srow) * 320 + (it+1)*32 + scol];

        h8v af[4];
        #pragma unroll
        for (int mi = 0; mi < 4; ++mi)
            af[mi] = *(const h8v*)&As[cur][wm*64 + mi*16 + r16][q*8];
        #pragma unroll
        for (int mi = 0; mi < 4; ++mi)
            #pragma unroll
            for (int ni = 0; ni < 2; ++ni)
                acc[mi][ni] = __builtin_amdgcn_mfma_f32_16x16x32_f16(
                                  af[mi], Bf[ni][it], acc[mi][ni], 0, 0, 0);

        if (it + 1 < 10)
            *(h8v*)&As[cur ^ 1][srow][scol] = av;
        __syncthreads();
    }

    #pragma unroll
    for (int ni = 0; ni < 2; ++ni) {
        int n = n0 + wn*32 + ni*16 + r16;
        if (n >= G4v) continue;
        float bn = bias[n];
        #pragma unroll
        for (int mi = 0; mi < 4; ++mi) {
            #pragma unroll
            for (int r = 0; r < 4; ++r) {
                int row = m0 + wm*64 + mi*16 + q*4 + r;
                int b   = row >> 7;
                int s   = row & 127;
                Gout[(((size_t)dir * Sv + s) * Bv + b) * G4v + n] =
                    (_Float16)(acc[mi][ni][r] + bn);
            }
        }
    }
}

// ------------------------------------------------------------------
// fast transcendentals (validated r8/r9: absmax unchanged at 0.03125)
// ------------------------------------------------------------------
__device__ __forceinline__ float sigm_f(float x)
{
    return __builtin_amdgcn_rcpf(1.f + __expf(-x));
}
__device__ __forceinline__ float tanh_f(float x)
{
    float e = __expf(-2.f * __builtin_fabsf(x));
    float r = (1.f - e) * __builtin_amdgcn_rcpf(1.f + e);
    return __builtin_copysignf(r, x);
}

// ------------------------------------------------------------------
// MFMA LSTM recurrence v6 = r9 kernel with the g_sh LDS round-trip
// replaced by an in-wave __shfl transpose (dst lane (q,cp) pulls reg q
// of lane cp). Everything else identical to the measured-196us r9.
// Do NOT raise launch_bounds occupancy (r10: (640,5)->48VGPR->spill).
// ------------------------------------------------------------------
__global__ __launch_bounds__(640, 1)
void lstm_mfma_k(const _Float16* __restrict__ G16,  // [2][S][B][600] fp16
                 const float* __restrict__ Wh_f, const float* __restrict__ Wh_b,
                 float* __restrict__ out_src,       // [B][S][300]
                 float* __restrict__ out_cell)      // [B][300]
{
    const int blk = blockIdx.x;          // 0..127
    const int dir = blk & 1;
    const int b0  = (blk >> 1) * 4;
    const float* Wh = dir ? Wh_b : Wh_f;
    const _Float16* Gd = G16 + (size_t)dir * Sv * Bv * G4v;

    const int tid  = threadIdx.x;
    const int w    = tid >> 6;           // wave 0..9
    const int lane = tid & 63;
    const int q    = lane >> 4;          // 0..3
    const int cp   = lane & 15;          // 0..15
    const int hcol = w * 16 + cp;        // 0..159
    const bool colok = (hcol < Hv);
    const int hc   = colok ? hcol : 0;
    const int rp   = q;                  // batch row this lane owns

    __shared__ _Float16 h_sh[2][16][168];

    // ---- one-time: Wh B-fragments in registers ----
    h8v Bf[4][5];
    #pragma unroll
    for (int g = 0; g < 4; ++g) {
        #pragma unroll
        for (int ks = 0; ks < 5; ++ks) {
            h8v v;
            #pragma unroll
            for (int j = 0; j < 8; ++j) {
                int k = 32*ks + 8*q + j;
                float x = (k < Hv && colok) ? Wh[(size_t)k * G4v + g*Hv + hcol] : 0.f;
                v[j] = (_Float16)x;
            }
            Bf[g][ks] = v;
        }
    }

    for (int i = tid; i < 2*16*168; i += 640)
        ((_Float16*)h_sh)[i] = (_Float16)0.f;

    float c = 0.f;

    // ---- prologue: prefetch G for steps 0 and 1 (depth 2) ----
    _Float16 gA[4], gB[4];
    {
        int ss0 = dir ? (Sv - 1) : 0;
        int ss1 = dir ? (Sv - 2) : 1;
        const _Float16* p0 = Gd + ((size_t)ss0 * Bv + b0 + rp) * G4v;
        const _Float16* p1 = Gd + ((size_t)ss1 * Bv + b0 + rp) * G4v;
        #pragma unroll
        for (int g = 0; g < 4; ++g) {
            gA[g] = p0[g*Hv + hc];
            gB[g] = p1[g*Hv + hc];
        }
    }
    __syncthreads();

    int cur = 0;
    for (int s = 0; s < Sv; ++s) {
        const int ss = dir ? (Sv - 1 - s) : s;

        // ---- prefetch G for step s+2 ----
        _Float16 gC[4];
        #pragma unroll
        for (int g = 0; g < 4; ++g) gC[g] = (_Float16)0.f;
        if (s + 2 < Sv) {
            int ss2 = dir ? (ss - 2) : (ss + 2);
            const _Float16* p = Gd + ((size_t)ss2 * Bv + b0 + rp) * G4v;
            #pragma unroll
            for (int g = 0; g < 4; ++g) gC[g] = p[g*Hv + hc];
        }

        // ---- MFMA: h @ Wh (A = h from LDS, B = Wh registers) ----
        f4v a0 = {0.f,0.f,0.f,0.f}, a1 = a0, a2 = a0, a3 = a0;
        #pragma unroll
        for (int ks = 0; ks < 5; ++ks) {
            h8v af = *(const h8v*)&h_sh[cur][cp][32*ks + 8*q];
            a0 = __builtin_amdgcn_mfma_f32_16x16x32_f16(af, Bf[0][ks], a0, 0, 0, 0);
            a1 = __builtin_amdgcn_mfma_f32_16x16x32_f16(af, Bf[1][ks], a1, 0, 0, 0);
            a2 = __builtin_amdgcn_mfma_f32_16x16x32_f16(af, Bf[2][ks], a2, 0, 0, 0);
            a3 = __builtin_amdgcn_mfma_f32_16x16x32_f16(af, Bf[3][ks], a3, 0, 0, 0);
        }

        // ---- in-wave transpose via shfl: need reg q of lane cp ----
        float g4[4];
        {
            float t0, t1, t2, t3;
            t0 = __shfl(a0[0], cp, 64); t1 = __shfl(a0[1], cp, 64);
            t2 = __shfl(a0[2], cp, 64); t3 = __shfl(a0[3], cp, 64);
            g4[0] = (q == 0) ? t0 : (q == 1) ? t1 : (q == 2) ? t2 : t3;
            t0 = __shfl(a1[0], cp, 64); t1 = __shfl(a1[1], cp, 64);
            t2 = __shfl(a1[2], cp, 64); t3 = __shfl(a1[3], cp, 64);
            g4[1] = (q == 0) ? t0 : (q == 1) ? t1 : (q == 2) ? t2 : t3;
            t0 = __shfl(a2[0], cp, 64); t1 = __shfl(a2[1], cp, 64);
            t2 = __shfl(a2[2], cp, 64); t3 = __shfl(a2[3], cp, 64);
            g4[2] = (q == 0) ? t0 : (q == 1) ? t1 : (q == 2) ? t2 : t3;
            t0 = __shfl(a3[0], cp, 64); t1 = __shfl(a3[1], cp, 64);
            t2 = __shfl(a3[2], cp, 64); t3 = __shfl(a3[3], cp, 64);
            g4[3] = (q == 0) ? t0 : (q == 1) ? t1 : (q == 2) ? t2 : t3;
        }
        float gi = g4[0] + (float)gA[0];
        float gf = g4[1] + (float)gA[1];
        float gg = g4[2] + (float)gA[2];
        float go = g4[3] + (float)gA[3];

        float I  = sigm_f(gi);
        float F  = sigm_f(gf);
        float Gt = tanh_f(gg);
        float O  = sigm_f(go);
        c = F * c + I * Gt;
        float h = O * tanh_f(c);

        h_sh[cur ^ 1][rp][hcol] = (_Float16)h;
        if (colok)
            out_src[(((size_t)(b0 + rp)) * Sv + ss) * (2*Hv) + dir*Hv + hcol] = h;

        #pragma unroll
        for (int g = 0; g < 4; ++g) { gA[g] = gB[g]; gB[g] = gC[g]; }
        cur ^= 1;

        // lgkmcnt-only barrier (LDS visibility; VMEM prefetch stays in flight)
        asm volatile("s_waitcnt lgkmcnt(0)" ::: "memory");
        __builtin_amdgcn_s_barrier();
        __builtin_amdgcn_sched_barrier(0);
    }

    if (colok)
        out_cell[(size_t)(b0 + rp) * (2*Hv) + dir*Hv + hcol] = c;
}

// ------------------------------------------------------------------
// transpose src_encoding: out_src fp32 [B][S][300] -> fp16 [B][320][128]
// (single plane; fp16 rel err 5e-4 * K=128 -> ~2e-3 abs, well in budget)
// ------------------------------------------------------------------
__global__ __launch_bounds__(256)
void trans_enc_k(const float* __restrict__ enc, _Float16* __restrict__ e16)
{
    const int b  = blockIdx.z;
    const int s0 = blockIdx.x * 64;
    const int n0 = blockIdx.y * 64;
    __shared__ float t[64][65];
    const int tid = threadIdx.x;
    const int j  = tid & 63;
    const int i0 = (tid >> 6) * 16;
    #pragma unroll
    for (int ii = 0; ii < 16; ++ii) {
        int i = i0 + ii;
        int n = n0 + j;
        t[i][j] = (n < Dv) ? enc[((size_t)b*Sv + s0 + i)*Dv + n] : 0.f;
    }
    __syncthreads();
    #pragma unroll
    for (int ii = 0; ii < 16; ++ii) {
        int nr = i0 + ii;
        e16[((size_t)b*320 + n0 + nr)*128 + s0 + j] = (_Float16)t[j][nr];
    }
}

// ------------------------------------------------------------------
// FUSED cosine-sim + context + type-encoder:
// phase 1: P[m][s] = (cmp16[b,m,:].src16[b,s,:])/(cn*sn) -> LDS (fp16)
// phase 2: out[b][m][n] = emb + bias + hot@W + sum_s P[m][s]*enc16[b,n,s]
// block = (mtile 64, batch). 256 thr / 4 waves.
// ------------------------------------------------------------------
__global__ __launch_bounds__(256)
void gemm_simctx_k(const _Float16* __restrict__ cmp16,  // [Bz][M][320]
                   const _Float16* __restrict__ src16,  // [B][128][320]
                   const float* __restrict__ cn, const float* __restrict__ sn,
                   const _Float16* __restrict__ enc16,  // [B][320][128]
                   const float* __restrict__ emb,       // [Bz][M][300]
                   const float* __restrict__ hot,       // [Bz][M][hd]
                   const float* __restrict__ W,         // [hd][300]
                   const float* __restrict__ bias,      // [300]
                   int M, int hd, float* __restrict__ outp)
{
    const int b   = blockIdx.z;
    const int m0  = blockIdx.x * 64;
    const int tid = threadIdx.x;
    const int lane = tid & 63;
    const int w  = tid >> 6;           // 0..3
    const int q  = lane >> 4, cp = lane & 15;

    __shared__ _Float16 Acmp[64][40];
    __shared__ _Float16 Bsrc[128][40];
    __shared__ _Float16 P_lds[64][136];
    __shared__ float Wsh[9*304];
    __shared__ float bsh[304];
    __shared__ float hotsh[64*9];

    // stage W/bias/hot once (covered by first k-loop barrier)
    for (int i = tid; i < hd*304; i += 256) {
        int jj = i / 304, nn = i - jj*304;
        Wsh[i] = (nn < Dv) ? W[(size_t)jj * Dv + nn] : 0.f;
    }
    for (int i = tid; i < 304; i += 256) bsh[i] = (i < Dv) ? bias[i] : 0.f;
    for (int i = tid; i < 64*hd; i += 256) hotsh[i] = hot[((size_t)b*M + m0)*hd + i];

    const _Float16* A  = cmp16 + ((size_t)b * M + m0) * 320;
    const _Float16* Bm = src16 + (size_t)b * 128 * 320;

    const int ar = tid >> 2, ac = (tid & 3) * 8;   // cmp stage: 64 rows x 32
    const int br = tid >> 1, bc = (tid & 1) * 16;  // src stage: 128 rows x 32

    // ---- phase 1: P = cmp @ src^T, wave w owns rows [16w,16w+16) ----
    f4v acc[8];
    #pragma unroll
    for (int i = 0; i < 8; ++i) acc[i] = (f4v){0.f,0.f,0.f,0.f};

    for (int k0 = 0; k0 < 320; k0 += 32) {
        h8v av  = *(const h8v*)&A [(size_t)ar * 320 + k0 + ac];
        h8v bv0 = *(const h8v*)&Bm[(size_t)br * 320 + k0 + bc];
        h8v bv1 = *(const h8v*)&Bm[(size_t)br * 320 + k0 + bc + 8];
        __syncthreads();
        *(h8v*)&Acmp[ar][ac]     = av;
        *(h8v*)&Bsrc[br][bc]     = bv0;
        *(h8v*)&Bsrc[br][bc + 8] = bv1;
        __syncthreads();

        h8v af = *(const h8v*)&Acmp[w*16 + cp][q*8];
        #pragma unroll
        for (int ni = 0; ni < 8; ++ni) {
            h8v bf = *(const h8v*)&Bsrc[ni*16 + cp][q*8];
            acc[ni] = __builtin_amdgcn_mfma_f32_16x16x32_f16(af, bf, acc[ni], 0, 0, 0);
        }
    }

    // scale by 1/(cn*sn), cast fp16, store P to LDS
    float cnv[4], snv8[8];
    #pragma unroll
    for (int r = 0; r < 4; ++r)
        cnv[r] = cn[(size_t)b * M + m0 + w*16 + 4*q + r];
    #pragma unroll
    for (int ni = 0; ni < 8; ++ni)
        snv8[ni] = sn[(size_t)b * 128 + ni*16 + cp];
    #pragma unroll
    for (int ni = 0; ni < 8; ++ni) {
        #pragma unroll
        for (int r = 0; r < 4; ++r) {
            float v = acc[ni][r] / (cnv[r] * snv8[ni]);
            P_lds[w*16 + 4*q + r][ni*16 + cp] = (_Float16)v;
        }
    }
    __syncthreads();   // all waves' P visible

    // ---- phase 2: out = P @ enc16^T(+...), wave w owns cols [80w,80w+80) ----
    h8v af2[4][4];
    #pragma unroll
    for (int mi = 0; mi < 4; ++mi)
        #pragma unroll
        for (int ks = 0; ks < 4; ++ks)
            af2[mi][ks] = *(const h8v*)&P_lds[mi*16 + cp][32*ks + 8*q];

    f4v acc2[4][5];
    #pragma unroll
    for (int mi = 0; mi < 4; ++mi)
        #pragma unroll
        for (int nt = 0; nt < 5; ++nt) acc2[mi][nt] = (f4v){0.f,0.f,0.f,0.f};

    const int nbase = w * 80;
    #pragma unroll
    for (int nt = 0; nt < 5; ++nt) {
        int n = nbase + nt*16 + cp;
        const _Float16* bp = enc16 + ((size_t)b * 320 + n) * 128 + 8*q;
        h8v b0 = *(const h8v*)&bp[0];
        h8v b1 = *(const h8v*)&bp[32];
        h8v b2 = *(const h8v*)&bp[64];
        h8v b3 = *(const h8v*)&bp[96];
        #pragma unroll
        for (int mi = 0; mi < 4; ++mi) {
            acc2[mi][nt] = __builtin_amdgcn_mfma_f32_16x16x32_f16(af2[mi][0], b0, acc2[mi][nt], 0, 0, 0);
            acc2[mi][nt] = __builtin_amdgcn_mfma_f32_16x16x32_f16(af2[mi][1], b1, acc2[mi][nt], 0, 0, 0);
            acc2[mi][nt] = __builtin_amdgcn_mfma_f32_16x16x32_f16(af2[mi][2], b2, acc2[mi][nt], 0, 0, 0);
            acc2[mi][nt] = __builtin_amdgcn_mfma_f32_16x16x32_f16(af2[mi][3], b3, acc2[mi][nt], 0, 0, 0);
        }
    }

    // epilogue: + emb + bias + hot@W, write out
    #pragma unroll
    for (int nt = 0; nt < 5; ++nt) {
        int n = nbase + nt*16 + cp;
        if (n >= Dv) continue;
        float bn = bsh[n];
        #pragma unroll
        for (int mi = 0; mi < 4; ++mi) {
            #pragma unroll
            for (int r = 0; r < 4; ++r) {
                int ml = mi*16 + 4*q + r;
                int m  = m0 + ml;
                float v = acc2[mi][nt][r] + bn + emb[((size_t)b * M + m) * Dv + n];
                for (int jj = 0; jj < hd; ++jj)
                    v = fmaf(hotsh[ml*hd + jj], Wsh[jj*304 + n], v);
                outp[((size_t)b * M + m) * Dv + n] = v;
            }
        }
    }
}

// ------------------------------------------------------------------
extern "C" void kernel_launch(void* const* d_in, const int* in_sizes, int n_in,
                              void* d_out, int out_size, void* d_ws, size_t ws_size,
                              hipStream_t stream)
{
    (void)in_sizes; (void)n_in; (void)out_size; (void)ws_size;
    const float* src_emb = (const float*)d_in[0];
    const float* col_emb = (const float*)d_in[1];
    const float* tab_emb = (const float*)d_in[2];
    const float* col_hot = (const float*)d_in[3];
    const float* tab_hot = (const float*)d_in[4];
    const float* Wx_f = (const float*)d_in[5];
    const float* Wh_f = (const float*)d_in[6];
    const float* b_f  = (const float*)d_in[7];
    const float* Wx_b = (const float*)d_in[8];
    const float* Wh_b = (const float*)d_in[9];
    const float* b_b  = (const float*)d_in[10];
    const float* W_col = (const float*)d_in[11];
    const float* b_col = (const float*)d_in[12];
    const float* W_tab = (const float*)d_in[13];
    const float* b_tab = (const float*)d_in[14];

    float* out      = (float*)d_out;
    float* out_src  = out;                       // [256][128][300]
    float* out_col  = out + 9830400;             // [256][256][300]
    float* out_tab  = out + 29491200;            // [256][64][300]
    float* out_cell = out + 34406400;            // [256][300]

    // ws layout (float offsets). Staging lives in ws now because the fused
    // sim+ctx kernel WRITES out_col/out_tab while reading staging (the old
    // d_out staging would race across blocks).
    float* ws = (float*)d_ws;
    _Float16* Gbuf16 = (_Float16*)ws;                       // [0, 19.66M) fl
    _Float16* enc16  = (_Float16*)ws;                       // reuses dead Gbuf16
    _Float16* A16    = (_Float16*)(ws + 19660800);          // 32768x320 halves
    _Float16* col16  = (_Float16*)(ws + 24903680);          // 65536x320
    _Float16* tab16  = (_Float16*)(ws + 35389440);          // 16384x320
    float* sn = ws + 39321600;
    float* cn = sn + 32768;
    float* tn = cn + 65536;

    // W16T in the (dead until fused-ctx) out_col region; only gemm_xw reads it
    _Float16* W16T = (_Float16*)(out + 9830400);            // [2][640][320]

    // 0. fused fp16 conversion + norms
    fused_cn_k<<<32768/4, 256, 0, stream>>>(src_emb, 32768, A16,   sn);
    fused_cn_k<<<65536/4, 256, 0, stream>>>(col_emb, 65536, col16, cn);
    fused_cn_k<<<16384/4, 256, 0, stream>>>(tab_emb, 16384, tab16, tn);
    conv_w16_k<<<dim3(640, 2), 320, 0, stream>>>(Wx_f, Wx_b, W16T);

    // 1. input projection (MFMA v2, fp16 G output)
    gemm_xw_mfma_k<<<dim3(256, 5, 2), 512, 0, stream>>>(A16, W16T, b_f, b_b, Gbuf16);

    // 2. recurrence (v6: r9 + shfl transpose)
    lstm_mfma_k<<<128, 640, 0, stream>>>(Gbuf16, Wh_f, Wh_b, out_src, out_cell);

    // 3. transpose src_encoding -> fp16 [B][320][128] (G now dead)
    trans_enc_k<<<dim3(2, 5, 256), 256, 0, stream>>>(out_src, enc16);

    // 4. fused cosine-sim + context + type encoder
    gemm_simctx_k<<<dim3(4, 1, 256), 256, 0, stream>>>(
        col16, A16, cn, sn, enc16, col_emb, col_hot, W_col, b_col, 256, 9, out_col);
    gemm_simctx_k<<<dim3(1, 1, 256), 256, 0, stream>>>(
        tab16, A16, tn, sn, enc16, tab_emb, tab_hot, W_tab, b_tab, 64, 5, out_tab);
}

// Round 14
// 563.545 us; speedup vs baseline: 2.2532x; 1.0130x over previous
//
#include <hip/hip_runtime.h>
#include <math.h>

#define Bv 256
#define Sv 128
#define Cv 256
#define Tv 64
#define Dv 300
#define Hv 150
#define G4v 600   // 4*H

typedef _Float16 h8v __attribute__((ext_vector_type(8)));
typedef _Float16 h4v __attribute__((ext_vector_type(4)));
typedef float    f4v __attribute__((ext_vector_type(4)));

// ------------------------------------------------------------------
// FUSED x3: fp32 [rows][300] -> fp16 [rows][320] + row L2 norm, for
// src/col/tab in ONE launch (grid-partitioned; saves 2 launch overheads)
// ------------------------------------------------------------------
__global__ __launch_bounds__(256)
void fused_cn3_k(const float* __restrict__ Asrc, _Float16* __restrict__ src16, float* __restrict__ snrm,
                 const float* __restrict__ Acol, _Float16* __restrict__ col16, float* __restrict__ cnrm,
                 const float* __restrict__ Atab, _Float16* __restrict__ tab16, float* __restrict__ tnrm)
{
    int gtid = blockIdx.x * 256 + threadIdx.x;
    int row  = gtid >> 6;                       // 0 .. 114687
    int lane = threadIdx.x & 63;

    const float* A; _Float16* O; float* N; int r;
    if (row < 32768)       { A = Asrc; O = src16; N = snrm; r = row; }
    else if (row < 98304)  { A = Acol; O = col16; N = cnrm; r = row - 32768; }
    else                   { A = Atab; O = tab16; N = tnrm; r = row - 98304; }

    const float* rp = A + (size_t)r * Dv;
    _Float16*    op = O + (size_t)r * 320;
    float s = 0.f;
    #pragma unroll
    for (int i4 = lane; i4 < 80; i4 += 64) {
        int k = i4 * 4;
        float4 v = {0.f, 0.f, 0.f, 0.f};
        if (k < Dv) v = *(const float4*)&rp[k];
        h4v o;
        o[0] = (_Float16)v.x; o[1] = (_Float16)v.y;
        o[2] = (_Float16)v.z; o[3] = (_Float16)v.w;
        *(h4v*)&op[k] = o;
        s += v.x*v.x + v.y*v.y + v.z*v.z + v.w*v.w;
    }
    #pragma unroll
    for (int off = 32; off > 0; off >>= 1) s += __shfl_down(s, off, 64);
    if (lane == 0) N[r] = fmaxf(sqrtf(s), 1e-8f);
}

// ------------------------------------------------------------------
// Wx fp32 [300][600] -> W16T fp16 [dir][640][320] transposed, zero-padded
// ------------------------------------------------------------------
__global__ __launch_bounds__(320)
void conv_w16_k(const float* __restrict__ Wf, const float* __restrict__ Wb,
                _Float16* __restrict__ W16T)
{
    const int n   = blockIdx.x;      // 0..639
    const int dir = blockIdx.y;      // 0..1
    const int k   = threadIdx.x;     // 0..319
    const float* W = dir ? Wb : Wf;
    float v = (k < Dv && n < G4v) ? W[(size_t)k * G4v + n] : 0.f;
    W16T[((size_t)dir * 640 + n) * 320 + k] = (_Float16)v;
}

// ------------------------------------------------------------------
// MFMA input projection v3: r11 structure (B register-resident) + LDS-
// staged COALESCED epilogue. Each m-tile is exactly one batch (b =
// blockIdx.x, rows = s), so output is 128 G-rows x 256B contiguous:
// stage C in Cst[128][136] (pad kills write conflicts), then 1KB-dense
// h8v stores (n-tile 4: 88 halves = 11 exact h8v lanes).
// ------------------------------------------------------------------
__global__ __launch_bounds__(512)
void gemm_xw_mfma_k(const _Float16* __restrict__ A16,
                    const _Float16* __restrict__ W16T,
                    const float* __restrict__ bf, const float* __restrict__ bb,
                    _Float16* __restrict__ Gout)
{
    const int bq  = blockIdx.x;          // batch (m-tile == one batch)
    const int m0  = bq * 128;
    const int n0  = blockIdx.y * 128;
    const int dir = blockIdx.z;
    const float* bias = dir ? bb : bf;
    const _Float16* Wd = W16T + (size_t)dir * 640 * 320;

    __shared__ _Float16 As[2][128][40];
    __shared__ _Float16 Cst[128][136];

    const int tid  = threadIdx.x;
    const int lane = tid & 63;
    const int w    = tid >> 6;           // 0..7
    const int wm   = w >> 2, wn = w & 3;
    const int r16  = lane & 15, q = lane >> 4;
    const int srow = tid >> 2;
    const int scol = (tid & 3) * 8;

    h8v Bf[2][10];
    #pragma unroll
    for (int ni = 0; ni < 2; ++ni)
        #pragma unroll
        for (int ks = 0; ks < 10; ++ks)
            Bf[ni][ks] = *(const h8v*)&Wd[(size_t)(n0 + wn*32 + ni*16 + r16) * 320
                                          + 32*ks + 8*q];

    f4v acc[4][2];
    #pragma unroll
    for (int i = 0; i < 4; ++i)
        #pragma unroll
        for (int j = 0; j < 2; ++j) acc[i][j] = (f4v){0.f,0.f,0.f,0.f};

    *(h8v*)&As[0][srow][scol] = *(const h8v*)&A16[(size_t)(m0 + srow) * 320 + scol];
    __syncthreads();

    for (int it = 0; it < 10; ++it) {
        const int cur = it & 1;
        h8v av;
        if (it + 1 < 10)
            av = *(const h8v*)&A16[(size_t)(m0 + srow) * 320 + (it+1)*32 + scol];

        h8v af[4];
        #pragma unroll
        for (int mi = 0; mi < 4; ++mi)
            af[mi] = *(const h8v*)&As[cur][wm*64 + mi*16 + r16][q*8];
        #pragma unroll
        for (int mi = 0; mi < 4; ++mi)
            #pragma unroll
            for (int ni = 0; ni < 2; ++ni)
                acc[mi][ni] = __builtin_amdgcn_mfma_f32_16x16x32_f16(
                                  af[mi], Bf[ni][it], acc[mi][ni], 0, 0, 0);

        if (it + 1 < 10)
            *(h8v*)&As[cur ^ 1][srow][scol] = av;
        __syncthreads();
    }

    // stage C (+bias) into LDS: lane (q,r16) holds D[m=mi*16+4q+r][n=wn*32+ni*16+r16]
    #pragma unroll
    for (int ni = 0; ni < 2; ++ni) {
        int nl = wn*32 + ni*16 + r16;        // local n 0..127
        int n  = n0 + nl;
        float bn = (n < G4v) ? bias[n] : 0.f;
        #pragma unroll
        for (int mi = 0; mi < 4; ++mi) {
            #pragma unroll
            for (int r = 0; r < 4; ++r) {
                int ml = wm*64 + mi*16 + 4*q + r;
                Cst[ml][nl] = (_Float16)(acc[mi][ni][r] + bn);
            }
        }
    }
    __syncthreads();

    // coalesced write-out: 4 passes x (32 rows x 16 lanes x 16B)
    const int orow = tid >> 4;               // 0..31
    const int ocol = (tid & 15) * 8;         // halves
    const int nglob = n0 + ocol;
    #pragma unroll
    for (int pass = 0; pass < 4; ++pass) {
        int s = pass*32 + orow;              // G row (= sequence pos)
        if (nglob + 8 <= G4v) {
            _Float16* gp = Gout + (((size_t)dir * Sv + s) * Bv + bq) * G4v + nglob;
            *(h8v*)gp = *(const h8v*)&Cst[s][ocol];
        }
    }
}

// ------------------------------------------------------------------
// fast transcendentals (validated r8/r9: absmax unchanged at 0.03125)
// ------------------------------------------------------------------
__device__ __forceinline__ float sigm_f(float x)
{
    return __builtin_amdgcn_rcpf(1.f + __expf(-x));
}
__device__ __forceinline__ float tanh_f(float x)
{
    float e = __expf(-2.f * __builtin_fabsf(x));
    float r = (1.f - e) * __builtin_amdgcn_rcpf(1.f + e);
    return __builtin_copysignf(r, x);
}

// ------------------------------------------------------------------
// MFMA LSTM recurrence (FROZEN at r13: ~200us structural floor).
// 128 blocks x 4 batches, (640,1) [84 VGPR], fp16 G, depth-2 prefetch,
// shfl transpose, lgkmcnt-only barrier. Do NOT raise launch_bounds
// occupancy (r10: (640,5)->48VGPR->spill->895us).
// ------------------------------------------------------------------
__global__ __launch_bounds__(640, 1)
void lstm_mfma_k(const _Float16* __restrict__ G16,  // [2][S][B][600] fp16
                 const float* __restrict__ Wh_f, const float* __restrict__ Wh_b,
                 float* __restrict__ out_src,       // [B][S][300]
                 float* __restrict__ out_cell)      // [B][300]
{
    const int blk = blockIdx.x;          // 0..127
    const int dir = blk & 1;
    const int b0  = (blk >> 1) * 4;
    const float* Wh = dir ? Wh_b : Wh_f;
    const _Float16* Gd = G16 + (size_t)dir * Sv * Bv * G4v;

    const int tid  = threadIdx.x;
    const int w    = tid >> 6;           // wave 0..9
    const int lane = tid & 63;
    const int q    = lane >> 4;          // 0..3
    const int cp   = lane & 15;          // 0..15
    const int hcol = w * 16 + cp;        // 0..159
    const bool colok = (hcol < Hv);
    const int hc   = colok ? hcol : 0;
    const int rp   = q;                  // batch row this lane owns

    __shared__ _Float16 h_sh[2][16][168];

    h8v Bf[4][5];
    #pragma unroll
    for (int g = 0; g < 4; ++g) {
        #pragma unroll
        for (int ks = 0; ks < 5; ++ks) {
            h8v v;
            #pragma unroll
            for (int j = 0; j < 8; ++j) {
                int k = 32*ks + 8*q + j;
                float x = (k < Hv && colok) ? Wh[(size_t)k * G4v + g*Hv + hcol] : 0.f;
                v[j] = (_Float16)x;
            }
            Bf[g][ks] = v;
        }
    }

    for (int i = tid; i < 2*16*168; i += 640)
        ((_Float16*)h_sh)[i] = (_Float16)0.f;

    float c = 0.f;

    _Float16 gA[4], gB[4];
    {
        int ss0 = dir ? (Sv - 1) : 0;
        int ss1 = dir ? (Sv - 2) : 1;
        const _Float16* p0 = Gd + ((size_t)ss0 * Bv + b0 + rp) * G4v;
        const _Float16* p1 = Gd + ((size_t)ss1 * Bv + b0 + rp) * G4v;
        #pragma unroll
        for (int g = 0; g < 4; ++g) {
            gA[g] = p0[g*Hv + hc];
            gB[g] = p1[g*Hv + hc];
        }
    }
    __syncthreads();

    int cur = 0;
    for (int s = 0; s < Sv; ++s) {
        const int ss = dir ? (Sv - 1 - s) : s;

        _Float16 gC[4];
        #pragma unroll
        for (int g = 0; g < 4; ++g) gC[g] = (_Float16)0.f;
        if (s + 2 < Sv) {
            int ss2 = dir ? (ss - 2) : (ss + 2);
            const _Float16* p = Gd + ((size_t)ss2 * Bv + b0 + rp) * G4v;
            #pragma unroll
            for (int g = 0; g < 4; ++g) gC[g] = p[g*Hv + hc];
        }

        f4v a0 = {0.f,0.f,0.f,0.f}, a1 = a0, a2 = a0, a3 = a0;
        #pragma unroll
        for (int ks = 0; ks < 5; ++ks) {
            h8v af = *(const h8v*)&h_sh[cur][cp][32*ks + 8*q];
            a0 = __builtin_amdgcn_mfma_f32_16x16x32_f16(af, Bf[0][ks], a0, 0, 0, 0);
            a1 = __builtin_amdgcn_mfma_f32_16x16x32_f16(af, Bf[1][ks], a1, 0, 0, 0);
            a2 = __builtin_amdgcn_mfma_f32_16x16x32_f16(af, Bf[2][ks], a2, 0, 0, 0);
            a3 = __builtin_amdgcn_mfma_f32_16x16x32_f16(af, Bf[3][ks], a3, 0, 0, 0);
        }

        float g4[4];
        {
            float t0, t1, t2, t3;
            t0 = __shfl(a0[0], cp, 64); t1 = __shfl(a0[1], cp, 64);
            t2 = __shfl(a0[2], cp, 64); t3 = __shfl(a0[3], cp, 64);
            g4[0] = (q == 0) ? t0 : (q == 1) ? t1 : (q == 2) ? t2 : t3;
            t0 = __shfl(a1[0], cp, 64); t1 = __shfl(a1[1], cp, 64);
            t2 = __shfl(a1[2], cp, 64); t3 = __shfl(a1[3], cp, 64);
            g4[1] = (q == 0) ? t0 : (q == 1) ? t1 : (q == 2) ? t2 : t3;
            t0 = __shfl(a2[0], cp, 64); t1 = __shfl(a2[1], cp, 64);
            t2 = __shfl(a2[2], cp, 64); t3 = __shfl(a2[3], cp, 64);
            g4[2] = (q == 0) ? t0 : (q == 1) ? t1 : (q == 2) ? t2 : t3;
            t0 = __shfl(a3[0], cp, 64); t1 = __shfl(a3[1], cp, 64);
            t2 = __shfl(a3[2], cp, 64); t3 = __shfl(a3[3], cp, 64);
            g4[3] = (q == 0) ? t0 : (q == 1) ? t1 : (q == 2) ? t2 : t3;
        }
        float gi = g4[0] + (float)gA[0];
        float gf = g4[1] + (float)gA[1];
        float gg = g4[2] + (float)gA[2];
        float go = g4[3] + (float)gA[3];

        float I  = sigm_f(gi);
        float F  = sigm_f(gf);
        float Gt = tanh_f(gg);
        float O  = sigm_f(go);
        c = F * c + I * Gt;
        float h = O * tanh_f(c);

        h_sh[cur ^ 1][rp][hcol] = (_Float16)h;
        if (colok)
            out_src[(((size_t)(b0 + rp)) * Sv + ss) * (2*Hv) + dir*Hv + hcol] = h;

        #pragma unroll
        for (int g = 0; g < 4; ++g) { gA[g] = gB[g]; gB[g] = gC[g]; }
        cur ^= 1;

        asm volatile("s_waitcnt lgkmcnt(0)" ::: "memory");
        __builtin_amdgcn_s_barrier();
        __builtin_amdgcn_sched_barrier(0);
    }

    if (colok)
        out_cell[(size_t)(b0 + rp) * (2*Hv) + dir*Hv + hcol] = c;
}

// ------------------------------------------------------------------
// transpose src_encoding: out_src fp32 [B][S][300] -> fp16 [B][320][128]
// ------------------------------------------------------------------
__global__ __launch_bounds__(256)
void trans_enc_k(const float* __restrict__ enc, _Float16* __restrict__ e16)
{
    const int b  = blockIdx.z;
    const int s0 = blockIdx.x * 64;
    const int n0 = blockIdx.y * 64;
    __shared__ float t[64][65];
    const int tid = threadIdx.x;
    const int j  = tid & 63;
    const int i0 = (tid >> 6) * 16;
    #pragma unroll
    for (int ii = 0; ii < 16; ++ii) {
        int i = i0 + ii;
        int n = n0 + j;
        t[i][j] = (n < Dv) ? enc[((size_t)b*Sv + s0 + i)*Dv + n] : 0.f;
    }
    __syncthreads();
    #pragma unroll
    for (int ii = 0; ii < 16; ++ii) {
        int nr = i0 + ii;
        e16[((size_t)b*320 + n0 + nr)*128 + s0 + j] = (_Float16)t[j][nr];
    }
}

// ------------------------------------------------------------------
// FUSED cosine-sim + context + type-encoder (r13, kept)
// ------------------------------------------------------------------
__global__ __launch_bounds__(256)
void gemm_simctx_k(const _Float16* __restrict__ cmp16,  // [Bz][M][320]
                   const _Float16* __restrict__ src16,  // [B][128][320]
                   const float* __restrict__ cn, const float* __restrict__ sn,
                   const _Float16* __restrict__ enc16,  // [B][320][128]
                   const float* __restrict__ emb,       // [Bz][M][300]
                   const float* __restrict__ hot,       // [Bz][M][hd]
                   const float* __restrict__ W,         // [hd][300]
                   const float* __restrict__ bias,      // [300]
                   int M, int hd, float* __restrict__ outp)
{
    const int b   = blockIdx.z;
    const int m0  = blockIdx.x * 64;
    const int tid = threadIdx.x;
    const int lane = tid & 63;
    const int w  = tid >> 6;           // 0..3
    const int q  = lane >> 4, cp = lane & 15;

    __shared__ _Float16 Acmp[64][40];
    __shared__ _Float16 Bsrc[128][40];
    __shared__ _Float16 P_lds[64][136];
    __shared__ float Wsh[9*304];
    __shared__ float bsh[304];
    __shared__ float hotsh[64*9];

    for (int i = tid; i < hd*304; i += 256) {
        int jj = i / 304, nn = i - jj*304;
        Wsh[i] = (nn < Dv) ? W[(size_t)jj * Dv + nn] : 0.f;
    }
    for (int i = tid; i < 304; i += 256) bsh[i] = (i < Dv) ? bias[i] : 0.f;
    for (int i = tid; i < 64*hd; i += 256) hotsh[i] = hot[((size_t)b*M + m0)*hd + i];

    const _Float16* A  = cmp16 + ((size_t)b * M + m0) * 320;
    const _Float16* Bm = src16 + (size_t)b * 128 * 320;

    const int ar = tid >> 2, ac = (tid & 3) * 8;
    const int br = tid >> 1, bc = (tid & 1) * 16;

    f4v acc[8];
    #pragma unroll
    for (int i = 0; i < 8; ++i) acc[i] = (f4v){0.f,0.f,0.f,0.f};

    for (int k0 = 0; k0 < 320; k0 += 32) {
        h8v av  = *(const h8v*)&A [(size_t)ar * 320 + k0 + ac];
        h8v bv0 = *(const h8v*)&Bm[(size_t)br * 320 + k0 + bc];
        h8v bv1 = *(const h8v*)&Bm[(size_t)br * 320 + k0 + bc + 8];
        __syncthreads();
        *(h8v*)&Acmp[ar][ac]     = av;
        *(h8v*)&Bsrc[br][bc]     = bv0;
        *(h8v*)&Bsrc[br][bc + 8] = bv1;
        __syncthreads();

        h8v af = *(const h8v*)&Acmp[w*16 + cp][q*8];
        #pragma unroll
        for (int ni = 0; ni < 8; ++ni) {
            h8v bf = *(const h8v*)&Bsrc[ni*16 + cp][q*8];
            acc[ni] = __builtin_amdgcn_mfma_f32_16x16x32_f16(af, bf, acc[ni], 0, 0, 0);
        }
    }

    float cnv[4], snv8[8];
    #pragma unroll
    for (int r = 0; r < 4; ++r)
        cnv[r] = cn[(size_t)b * M + m0 + w*16 + 4*q + r];
    #pragma unroll
    for (int ni = 0; ni < 8; ++ni)
        snv8[ni] = sn[(size_t)b * 128 + ni*16 + cp];
    #pragma unroll
    for (int ni = 0; ni < 8; ++ni) {
        #pragma unroll
        for (int r = 0; r < 4; ++r) {
            float v = acc[ni][r] / (cnv[r] * snv8[ni]);
            P_lds[w*16 + 4*q + r][ni*16 + cp] = (_Float16)v;
        }
    }
    __syncthreads();

    h8v af2[4][4];
    #pragma unroll
    for (int mi = 0; mi < 4; ++mi)
        #pragma unroll
        for (int ks = 0; ks < 4; ++ks)
            af2[mi][ks] = *(const h8v*)&P_lds[mi*16 + cp][32*ks + 8*q];

    f4v acc2[4][5];
    #pragma unroll
    for (int mi = 0; mi < 4; ++mi)
        #pragma unroll
        for (int nt = 0; nt < 5; ++nt) acc2[mi][nt] = (f4v){0.f,0.f,0.f,0.f};

    const int nbase = w * 80;
    #pragma unroll
    for (int nt = 0; nt < 5; ++nt) {
        int n = nbase + nt*16 + cp;
        const _Float16* bp = enc16 + ((size_t)b * 320 + n) * 128 + 8*q;
        h8v b0 = *(const h8v*)&bp[0];
        h8v b1 = *(const h8v*)&bp[32];
        h8v b2 = *(const h8v*)&bp[64];
        h8v b3 = *(const h8v*)&bp[96];
        #pragma unroll
        for (int mi = 0; mi < 4; ++mi) {
            acc2[mi][nt] = __builtin_amdgcn_mfma_f32_16x16x32_f16(af2[mi][0], b0, acc2[mi][nt], 0, 0, 0);
            acc2[mi][nt] = __builtin_amdgcn_mfma_f32_16x16x32_f16(af2[mi][1], b1, acc2[mi][nt], 0, 0, 0);
            acc2[mi][nt] = __builtin_amdgcn_mfma_f32_16x16x32_f16(af2[mi][2], b2, acc2[mi][nt], 0, 0, 0);
            acc2[mi][nt] = __builtin_amdgcn_mfma_f32_16x16x32_f16(af2[mi][3], b3, acc2[mi][nt], 0, 0, 0);
        }
    }

    #pragma unroll
    for (int nt = 0; nt < 5; ++nt) {
        int n = nbase + nt*16 + cp;
        if (n >= Dv) continue;
        float bn = bsh[n];
        #pragma unroll
        for (int mi = 0; mi < 4; ++mi) {
            #pragma unroll
            for (int r = 0; r < 4; ++r) {
                int ml = mi*16 + 4*q + r;
                int m  = m0 + ml;
                float v = acc2[mi][nt][r] + bn + emb[((size_t)b * M + m) * Dv + n];
                for (int jj = 0; jj < hd; ++jj)
                    v = fmaf(hotsh[ml*hd + jj], Wsh[jj*304 + n], v);
                outp[((size_t)b * M + m) * Dv + n] = v;
            }
        }
    }
}

// ------------------------------------------------------------------
extern "C" void kernel_launch(void* const* d_in, const int* in_sizes, int n_in,
                              void* d_out, int out_size, void* d_ws, size_t ws_size,
                              hipStream_t stream)
{
    (void)in_sizes; (void)n_in; (void)out_size; (void)ws_size;
    const float* src_emb = (const float*)d_in[0];
    const float* col_emb = (const float*)d_in[1];
    const float* tab_emb = (const float*)d_in[2];
    const float* col_hot = (const float*)d_in[3];
    const float* tab_hot = (const float*)d_in[4];
    const float* Wx_f = (const float*)d_in[5];
    const float* Wh_f = (const float*)d_in[6];
    const float* b_f  = (const float*)d_in[7];
    const float* Wx_b = (const float*)d_in[8];
    const float* Wh_b = (const float*)d_in[9];
    const float* b_b  = (const float*)d_in[10];
    const float* W_col = (const float*)d_in[11];
    const float* b_col = (const float*)d_in[12];
    const float* W_tab = (const float*)d_in[13];
    const float* b_tab = (const float*)d_in[14];

    float* out      = (float*)d_out;
    float* out_src  = out;                       // [256][128][300]
    float* out_col  = out + 9830400;             // [256][256][300]
    float* out_tab  = out + 29491200;            // [256][64][300]
    float* out_cell = out + 34406400;            // [256][300]

    float* ws = (float*)d_ws;
    _Float16* Gbuf16 = (_Float16*)ws;                       // [0, 19.66M) fl
    _Float16* enc16  = (_Float16*)ws;                       // reuses dead Gbuf16
    _Float16* A16    = (_Float16*)(ws + 19660800);          // 32768x320 halves
    _Float16* col16  = (_Float16*)(ws + 24903680);          // 65536x320
    _Float16* tab16  = (_Float16*)(ws + 35389440);          // 16384x320
    float* sn = ws + 39321600;
    float* cn = sn + 32768;
    float* tn = cn + 65536;

    // W16T in the (dead until fused-ctx) out_col region; only gemm_xw reads it
    _Float16* W16T = (_Float16*)(out + 9830400);            // [2][640][320]

    // 0. fused fp16 conversion + norms (ONE launch for src/col/tab)
    fused_cn3_k<<<114688/4, 256, 0, stream>>>(src_emb, A16, sn,
                                              col_emb, col16, cn,
                                              tab_emb, tab16, tn);
    conv_w16_k<<<dim3(640, 2), 320, 0, stream>>>(Wx_f, Wx_b, W16T);

    // 1. input projection (MFMA v3, coalesced epilogue, fp16 G output)
    gemm_xw_mfma_k<<<dim3(256, 5, 2), 512, 0, stream>>>(A16, W16T, b_f, b_b, Gbuf16);

    // 2. recurrence (frozen r13 kernel)
    lstm_mfma_k<<<128, 640, 0, stream>>>(Gbuf16, Wh_f, Wh_b, out_src, out_cell);

    // 3. transpose src_encoding -> fp16 [B][320][128] (G now dead)
    trans_enc_k<<<dim3(2, 5, 256), 256, 0, stream>>>(out_src, enc16);

    // 4. fused cosine-sim + context + type encoder
    gemm_simctx_k<<<dim3(4, 1, 256), 256, 0, stream>>>(
        col16, A16, cn, sn, enc16, col_emb, col_hot, W_col, b_col, 256, 9, out_col);
    gemm_simctx_k<<<dim3(1, 1, 256), 256, 0, stream>>>(
        tab16, A16, tn, sn, enc16, tab_emb, tab_hot, W_tab, b_tab, 64, 5, out_tab);
}